// Round 2
// baseline (699.327 us; speedup 1.0000x reference)
//
#include <hip/hip_runtime.h>
#include <hip/hip_bf16.h>

// GCN_5016521802361: 2x SAGEConv(aggr='lstm', project=True), N=50000, D=16, F=128, C=40.
// Round 15: lstm_aggr drops the Y-stage LDS entirely.
//  - Each thread's 16 gate values = 2 contiguous 16B chunks of row srcl[t][lid]
//    (bytes [w*128+q*32, +32)); loaded directly global->VGPR with 1-step register
//    prefetch (issue after consuming the current pair; compiler-counted vmcnt).
//    Same 128B-line coalescing as the old DMA; removes 2 DMA + 2 stage
//    ds_read_b128 + their ~4-way structural conflicts per wave-step, and the
//    whole vmcnt choreography. LDS: 42.5KB -> 9.7KB.
//  - Loop fully unrolled (static t): t=0 (no recurrent MFMA) / t=15 (aggr store)
//    specialization branch-free; srcl indexing static.
//  - Occupancy note: combined regs ~120 (56 VGPR + 64 AGPR wf) -> 4 waves/SIMD
//    (2 blocks/CU) is the structural ceiling; wf-in-reg is mandatory.
//  - exp2-prescale cell (r14) retained: 5 native v_exp + 2 rcp per cell.

typedef __hip_bfloat16 bf16;
typedef __attribute__((ext_vector_type(8))) short short8;
typedef __attribute__((ext_vector_type(4))) short short4v;
typedef __attribute__((ext_vector_type(4))) float floatx4;

#define LOG2E 1.4426950408889634f
#define TWOL  2.8853900817779268f

__device__ __forceinline__ float bf2f(bf16 v) { return __bfloat162float(v); }
__device__ __forceinline__ bf16  f2bf(float v) { return __float2bfloat16(v); }
__device__ __forceinline__ float bfs2f(short s) {
    union { float f; unsigned u; } v; v.u = ((unsigned)(unsigned short)s) << 16; return v.f;
}
__device__ __forceinline__ short f2bfs(float v) {
    bf16 b = __float2bfloat16(v); return *(short*)&b;
}

__device__ __forceinline__ float ex2(float x) {
#if __has_builtin(__builtin_amdgcn_exp2f)
    return __builtin_amdgcn_exp2f(x);
#else
    return exp2f(x);
#endif
}

// LSTM cell, prescaled inputs: i_,f_,o_ carry log2e, g_ carries 2*log2e,
// c is tracked as (2*log2e)*c_true. Single merged rcp on the c path.
__device__ __forceinline__ float cell(float i_, float f_, float g_, float o_, float& c) {
    float ei = ex2(-i_), ef = ex2(-f_), eg = ex2(g_), eo = ex2(-o_);
    float A = (1.f + ei) * (eg + 1.f);
    float B = 1.f + ef;
    // c'' = [c''*A + 2L*(eg-1)*B] / (A*B)
    float cn = fmaf(c, A, fmaf(eg, TWOL, -TWOL) * B) * __builtin_amdgcn_rcpf(A * B);
    c = cn;
    float ec = ex2(cn);
    return (ec - 1.f) * __builtin_amdgcn_rcpf((ec + 1.f) * (1.f + eo));
}

// Permuted-Y memory position p <-> gate column: p = w*64 + q*16 + g*4 + r where
// the gate col cg = g*128 + (16w + 4q + r). Writers decode p -> source row.
__device__ __forceinline__ int ydecode(int p) {
    int pw = (p >> 6) & 7, pq = (p >> 4) & 3, pg = (p >> 2) & 3, pr = p & 3;
    return pg * 128 + pw * 16 + pq * 4 + pr;
}

__global__ void detect_dtype(const unsigned short* __restrict__ xb, int* __restrict__ flag) {
    int cnt = 0;
    for (int i = threadIdx.x; i < 1024; i += 64) {
        int e = (xb[i] >> 7) & 0xFF;
        cnt += (e >= 0xC8);
    }
#pragma unroll
    for (int off = 32; off; off >>= 1) cnt += __shfl_down(cnt, off);
    if (threadIdx.x == 0) *flag = (cnt >= 16) ? 1 : 0;   // 1 => inputs are float32
}

struct Cvt { const void* src; bf16* dst; int n; int gs; };
struct CvtAll { Cvt t[19]; };

__global__ void convert_inputs(CvtAll ca, const int* __restrict__ flag) {
    const bool isf32 = (*flag != 0);
    const int stride = gridDim.x * blockDim.x;
    const int tid0 = blockIdx.x * blockDim.x + threadIdx.x;
#pragma unroll 1
    for (int k = 0; k < 19; k++) {
        const int n = ca.t[k].n, gs = ca.t[k].gs;
        const float* sf = (const float*)ca.t[k].src;
        const bf16*  sb = (const bf16*)ca.t[k].src;
        bf16* d = ca.t[k].dst;
        for (int i = tid0; i < n; i += stride) {
            float v = isf32 ? sf[i] : bf2f(sb[i]);
            if (gs) v *= ((((unsigned)i >> gs) & 3) == 2) ? TWOL : LOG2E;
            d[i] = f2bf(v);
        }
    }
}

// generic (final lin2 layer)
template <int NCT, bool RELU, bool BIAS2, bool DUAL, bool OUTF>
__global__ __launch_bounds__(256, 2) void gemm_bias(
    const bf16* __restrict__ A, const bf16* __restrict__ B,
    const bf16* __restrict__ bias, const bf16* __restrict__ bias2,
    const bf16* __restrict__ A2, const bf16* __restrict__ B2,
    void* __restrict__ Cv, const int* __restrict__ oflag,
    int N, int nbt, int ldc)
{
    const int tid = threadIdx.x;
    const int w = tid >> 6, l = tid & 63, q = l >> 4, lid = l & 15;
    const int rowbase = blockIdx.x * 64 + w * 16;
    const int colslice = blockIdx.y * (NCT * 16);

    int arow = rowbase + lid;
    if (arow >= N) arow = N - 1;

    floatx4 acc[NCT];
#pragma unroll
    for (int ct = 0; ct < NCT; ct++) acc[ct] = (floatx4)(0.f);

    short8 bfrag[NCT][4];
#pragma unroll
    for (int ct = 0; ct < NCT; ct++) {
        int j = colslice + ct * 16 + lid;
        if (j >= nbt) j = nbt - 1;
#pragma unroll
        for (int kt = 0; kt < 4; kt++)
            bfrag[ct][kt] = *(const short8*)(B + (size_t)j * 128 + kt * 32 + q * 8);
    }
#pragma unroll
    for (int kt = 0; kt < 4; kt++) {
        short8 af = *(const short8*)(A + (size_t)arow * 128 + kt * 32 + q * 8);
#pragma unroll
        for (int ct = 0; ct < NCT; ct++)
            acc[ct] = __builtin_amdgcn_mfma_f32_16x16x32_bf16(af, bfrag[ct][kt], acc[ct], 0, 0, 0);
    }
    if constexpr (DUAL) {
#pragma unroll
        for (int ct = 0; ct < NCT; ct++) {
            int j = colslice + ct * 16 + lid;
            if (j >= nbt) j = nbt - 1;
#pragma unroll
            for (int kt = 0; kt < 4; kt++)
                bfrag[ct][kt] = *(const short8*)(B2 + (size_t)j * 128 + kt * 32 + q * 8);
        }
#pragma unroll
        for (int kt = 0; kt < 4; kt++) {
            short8 af = *(const short8*)(A2 + (size_t)arow * 128 + kt * 32 + q * 8);
#pragma unroll
            for (int ct = 0; ct < NCT; ct++)
                acc[ct] = __builtin_amdgcn_mfma_f32_16x16x32_bf16(af, bfrag[ct][kt], acc[ct], 0, 0, 0);
        }
    }
    bool of32 = false;
    if constexpr (OUTF) of32 = (*oflag != 0);
#pragma unroll
    for (int ct = 0; ct < NCT; ct++) {
        int cg = colslice + ct * 16 + lid;
        int cb = cg < nbt ? cg : nbt - 1;
        float bv = bf2f(bias[cb]);
        if constexpr (BIAS2) bv += bf2f(bias2[cb]);
#pragma unroll
        for (int r = 0; r < 4; r++) {
            int row = rowbase + q * 4 + r;
            float v = acc[ct][r] + bv;
            if constexpr (RELU) v = fmaxf(v, 0.f);
            if (row < N && cg < nbt) {
                size_t idx = (size_t)row * ldc + cg;
                if constexpr (OUTF) {
                    if (of32) ((float*)Cv)[idx] = v;
                    else      ((bf16*)Cv)[idx] = f2bf(v);
                } else {
                    ((bf16*)Cv)[idx] = f2bf(v);
                }
            }
        }
    }
}

// ---------------------------------------------------------------------------
// Fused layer entry: Y = (relu(X@Wp^T+bp)) @ Wih^T + bih + bhh, permuted layout
// via SOURCE-ROW indexing (Wih/bih/bhh arrive prescaled by log2e / 2*log2e).
// ---------------------------------------------------------------------------
__global__ __launch_bounds__(256, 2) void fused_xp_y(
    const bf16* __restrict__ X, const bf16* __restrict__ Wp, const bf16* __restrict__ bp,
    const bf16* __restrict__ Wih, const bf16* __restrict__ bih, const bf16* __restrict__ bhh,
    bf16* __restrict__ Yout, int N)
{
    __shared__ bf16 T[64][136];
    const int tid = threadIdx.x;
    const int w = tid >> 6, l = tid & 63, q = l >> 4, lid = l & 15;
    const int rowbase = blockIdx.x * 64;

    int arow = rowbase + w * 16 + lid;
    if (arow >= N) arow = N - 1;

    floatx4 acc[8];
    short8 bfrag[8][4];

    // ---- stage A: xp = relu(X@Wp^T + bp) -> T ----
#pragma unroll
    for (int ct = 0; ct < 8; ct++) acc[ct] = (floatx4)(0.f);
#pragma unroll
    for (int ct = 0; ct < 8; ct++) {
        int j = ct * 16 + lid;
#pragma unroll
        for (int kt = 0; kt < 4; kt++)
            bfrag[ct][kt] = *(const short8*)(Wp + (size_t)j * 128 + kt * 32 + q * 8);
    }
#pragma unroll
    for (int kt = 0; kt < 4; kt++) {
        short8 af = *(const short8*)(X + (size_t)arow * 128 + kt * 32 + q * 8);
#pragma unroll
        for (int ct = 0; ct < 8; ct++)
            acc[ct] = __builtin_amdgcn_mfma_f32_16x16x32_bf16(af, bfrag[ct][kt], acc[ct], 0, 0, 0);
    }
#pragma unroll
    for (int ct = 0; ct < 8; ct++) {
        int col = ct * 16 + lid;
        float bv = bf2f(bp[col]);
#pragma unroll
        for (int r = 0; r < 4; r++)
            T[w * 16 + q * 4 + r][col] = f2bf(fmaxf(acc[ct][r] + bv, 0.f));
    }
    __syncthreads();

    // ---- stage B: Y chunks, contiguous stores, permute via source-row index ----
#pragma unroll 1
    for (int cc = 0; cc < 4; cc++) {
#pragma unroll
        for (int ct = 0; ct < 8; ct++) {
            int jm = cc * 128 + ct * 16 + lid;      // memory column
            int src = ydecode(jm);                  // source gate row
#pragma unroll
            for (int kt = 0; kt < 4; kt++)
                bfrag[ct][kt] = *(const short8*)(Wih + (size_t)src * 128 + kt * 32 + q * 8);
        }
#pragma unroll
        for (int ct = 0; ct < 8; ct++) acc[ct] = (floatx4)(0.f);
#pragma unroll
        for (int kt = 0; kt < 4; kt++) {
            short8 af = *(const short8*)&T[w * 16 + lid][kt * 32 + q * 8];
#pragma unroll
            for (int ct = 0; ct < 8; ct++)
                acc[ct] = __builtin_amdgcn_mfma_f32_16x16x32_bf16(af, bfrag[ct][kt], acc[ct], 0, 0, 0);
        }
#pragma unroll
        for (int ct = 0; ct < 8; ct++) {
            int jm = cc * 128 + ct * 16 + lid;
            int src = ydecode(jm);
            float bv = bf2f(bih[src]) + bf2f(bhh[src]);
#pragma unroll
            for (int r = 0; r < 4; r++) {
                int row = rowbase + w * 16 + q * 4 + r;
                if (row < N) Yout[(size_t)row * 512 + jm] = f2bf(acc[ct][r] + bv);
            }
        }
    }
}

// ---------------------------------------------------------------------------
// Fused between-layers: h1 = relu(aggr@Wl^T+bl+X@Wr^T) (global+LDS);
// xp2 = relu(h1@Wp2^T+bp2) (LDS); Y2 = permuted via source-row indexing.
// ---------------------------------------------------------------------------
__global__ __launch_bounds__(256, 2) void fused_lin_xp_y(
    const bf16* __restrict__ aggr, const bf16* __restrict__ Wl, const bf16* __restrict__ bl,
    const bf16* __restrict__ X, const bf16* __restrict__ Wr,
    bf16* __restrict__ h1out,
    const bf16* __restrict__ Wp2, const bf16* __restrict__ bp2,
    const bf16* __restrict__ Wih2, const bf16* __restrict__ bih2, const bf16* __restrict__ bhh2,
    bf16* __restrict__ Yout, int N)
{
    __shared__ bf16 T1[64][136];
    __shared__ bf16 T2[64][136];
    const int tid = threadIdx.x;
    const int w = tid >> 6, l = tid & 63, q = l >> 4, lid = l & 15;
    const int rowbase = blockIdx.x * 64;

    int arow = rowbase + w * 16 + lid;
    if (arow >= N) arow = N - 1;

    floatx4 acc[8];
    short8 bfrag[8][4];

    // ---- stage A: h1 ----
#pragma unroll
    for (int ct = 0; ct < 8; ct++) acc[ct] = (floatx4)(0.f);
#pragma unroll
    for (int ct = 0; ct < 8; ct++) {
        int j = ct * 16 + lid;
#pragma unroll
        for (int kt = 0; kt < 4; kt++)
            bfrag[ct][kt] = *(const short8*)(Wl + (size_t)j * 128 + kt * 32 + q * 8);
    }
#pragma unroll
    for (int kt = 0; kt < 4; kt++) {
        short8 af = *(const short8*)(aggr + (size_t)arow * 128 + kt * 32 + q * 8);
#pragma unroll
        for (int ct = 0; ct < 8; ct++)
            acc[ct] = __builtin_amdgcn_mfma_f32_16x16x32_bf16(af, bfrag[ct][kt], acc[ct], 0, 0, 0);
    }
#pragma unroll
    for (int ct = 0; ct < 8; ct++) {
        int j = ct * 16 + lid;
#pragma unroll
        for (int kt = 0; kt < 4; kt++)
            bfrag[ct][kt] = *(const short8*)(Wr + (size_t)j * 128 + kt * 32 + q * 8);
    }
#pragma unroll
    for (int kt = 0; kt < 4; kt++) {
        short8 af = *(const short8*)(X + (size_t)arow * 128 + kt * 32 + q * 8);
#pragma unroll
        for (int ct = 0; ct < 8; ct++)
            acc[ct] = __builtin_amdgcn_mfma_f32_16x16x32_bf16(af, bfrag[ct][kt], acc[ct], 0, 0, 0);
    }
#pragma unroll
    for (int ct = 0; ct < 8; ct++) {
        int col = ct * 16 + lid;
        float bv = bf2f(bl[col]);
#pragma unroll
        for (int r = 0; r < 4; r++) {
            int rl = w * 16 + q * 4 + r;
            bf16 hv = f2bf(fmaxf(acc[ct][r] + bv, 0.f));
            T1[rl][col] = hv;
            int row = rowbase + rl;
            if (row < N) h1out[(size_t)row * 128 + col] = hv;
        }
    }
    __syncthreads();

    // ---- stage B: xp2 -> T2 ----
#pragma unroll
    for (int ct = 0; ct < 8; ct++) {
        int j = ct * 16 + lid;
#pragma unroll
        for (int kt = 0; kt < 4; kt++)
            bfrag[ct][kt] = *(const short8*)(Wp2 + (size_t)j * 128 + kt * 32 + q * 8);
    }
#pragma unroll
    for (int ct = 0; ct < 8; ct++) acc[ct] = (floatx4)(0.f);
#pragma unroll
    for (int kt = 0; kt < 4; kt++) {
        short8 af = *(const short8*)&T1[w * 16 + lid][kt * 32 + q * 8];
#pragma unroll
        for (int ct = 0; ct < 8; ct++)
            acc[ct] = __builtin_amdgcn_mfma_f32_16x16x32_bf16(af, bfrag[ct][kt], acc[ct], 0, 0, 0);
    }
#pragma unroll
    for (int ct = 0; ct < 8; ct++) {
        int col = ct * 16 + lid;
        float bv = bf2f(bp2[col]);
#pragma unroll
        for (int r = 0; r < 4; r++)
            T2[w * 16 + q * 4 + r][col] = f2bf(fmaxf(acc[ct][r] + bv, 0.f));
    }
    __syncthreads();

    // ---- stage C: Y2 chunks, contiguous stores, permute via source-row index ----
#pragma unroll 1
    for (int cc = 0; cc < 4; cc++) {
#pragma unroll
        for (int ct = 0; ct < 8; ct++) {
            int jm = cc * 128 + ct * 16 + lid;
            int src = ydecode(jm);
#pragma unroll
            for (int kt = 0; kt < 4; kt++)
                bfrag[ct][kt] = *(const short8*)(Wih2 + (size_t)src * 128 + kt * 32 + q * 8);
        }
#pragma unroll
        for (int ct = 0; ct < 8; ct++) acc[ct] = (floatx4)(0.f);
#pragma unroll
        for (int kt = 0; kt < 4; kt++) {
            short8 af = *(const short8*)&T2[w * 16 + lid][kt * 32 + q * 8];
#pragma unroll
            for (int ct = 0; ct < 8; ct++)
                acc[ct] = __builtin_amdgcn_mfma_f32_16x16x32_bf16(af, bfrag[ct][kt], acc[ct], 0, 0, 0);
        }
#pragma unroll
        for (int ct = 0; ct < 8; ct++) {
            int jm = cc * 128 + ct * 16 + lid;
            int src = ydecode(jm);
            float bv = bf2f(bih2[src]) + bf2f(bhh2[src]);
#pragma unroll
            for (int r = 0; r < 4; r++) {
                int row = rowbase + w * 16 + q * 4 + r;
                if (row < N) Yout[(size_t)row * 512 + jm] = f2bf(acc[ct][r] + bv);
            }
        }
    }
}

// ---------------------------------------------------------------------------
// LSTM neighbor aggregation, round-15 structure: direct register gather.
// 512 thr / 8 waves / 16 nodes; wave w owns hidden cols [16w,16w+16).
// Thread (w,q,lid) needs exactly permuted-Y elements [w*64+q*16, +16) of row
// srcl[t][lid] = 2 contiguous 16B loads (4 q-threads cover one 128B line/row).
// 1-step register prefetch: pair for t+1 issued right after pair t is consumed;
// latency hides under MFMA+cell+barrier. No Y LDS at all. hb double-buffered;
// per-step sync = lgkmcnt(0)+s_barrier (hb exchange only).
// ---------------------------------------------------------------------------
__global__ __launch_bounds__(512, 4) void lstm_aggr(
    const bf16* __restrict__ Y,     // [N,512] PERMUTED, prescaled pre-activations
    const int* __restrict__ esrc,   // [N,16]
    const bf16* __restrict__ Whh,   // [512,128] prescaled by gate
    bf16* __restrict__ aggr,        // [N,128] out: final h
    int N)
{
    __shared__ alignas(16) bf16 hb[2][16][136];
    __shared__ int srcl[16][16];    // [t][node]

    const int tid = threadIdx.x;
    const int w = tid >> 6, l = tid & 63, q = l >> 4, lid = l & 15;
    const int nodebase = blockIdx.x * 16;   // N = 50000 = 3125*16, exact

    if (tid < 256) {
        int node = tid >> 4, t = tid & 15;
        srcl[t][node] = esrc[(size_t)(nodebase + node) * 16 + t];
    }

    // Whh A-fragments: wf[g][kt]; A-row = gatecol = g*128 + 16*w + lid
    short8 wf[4][4];
#pragma unroll
    for (int g = 0; g < 4; g++) {
        int gc = g * 128 + 16 * w + lid;
#pragma unroll
        for (int kt = 0; kt < 4; kt++)
            wf[g][kt] = *(const short8*)(Whh + (size_t)gc * 128 + kt * 32 + q * 8);
    }

    float c[4];
#pragma unroll
    for (int r = 0; r < 4; r++) c[r] = 0.f;

    const int toff = w * 64 + q * 16;   // element offset of this thread's 32B

    __syncthreads();   // srcl visible

    short8 cur0, cur1;
    {
        const bf16* p = Y + (size_t)srcl[0][lid] * 512 + toff;
        cur0 = *(const short8*)p;
        cur1 = *(const short8*)(p + 8);
    }

#pragma unroll
    for (int t = 0; t < 16; t++) {
        const int cb = t & 1;

        // consume pair t (compiler inserts the vmcnt wait here)
        floatx4 acc[4];
#pragma unroll
        for (int g = 0; g < 2; g++)
#pragma unroll
            for (int r = 0; r < 4; r++) {
                acc[g][r]     = bfs2f(cur0[g * 4 + r]);
                acc[2 + g][r] = bfs2f(cur1[g * 4 + r]);
            }

        // issue pair t+1 immediately; hides under MFMA+cell+barrier
        if (t < 15) {
            const bf16* p = Y + (size_t)srcl[t + 1][lid] * 512 + toff;
            cur0 = *(const short8*)p;
            cur1 = *(const short8*)(p + 8);
        }

        if (t) {   // h0 = 0: skip recurrent MFMA at t=0
#pragma unroll
            for (int kt = 0; kt < 4; kt++) {
                short8 bh = *(const short8*)&hb[cb][lid][kt * 32 + q * 8];
#pragma unroll
                for (int g = 0; g < 4; g++)
                    acc[g] = __builtin_amdgcn_mfma_f32_16x16x32_bf16(wf[g][kt], bh, acc[g], 0, 0, 0);
            }
        }

        {
            short4v hv;
#pragma unroll
            for (int r = 0; r < 4; r++)
                hv[r] = f2bfs(cell(acc[0][r], acc[1][r], acc[2][r], acc[3][r], c[r]));
            if (t < 15) {
                *(short4v*)&hb[cb ^ 1][lid][16 * w + 4 * q] = hv;
                asm volatile("s_waitcnt lgkmcnt(0)" ::: "memory");
                __builtin_amdgcn_s_barrier();   // hb exchange only
            } else {
                *(short4v*)(aggr + (size_t)(nodebase + lid) * 128 + 16 * w + 4 * q) = hv;
            }
        }
    }
}

extern "C" void kernel_launch(void* const* d_in, const int* in_sizes, int n_in,
                              void* d_out, int out_size, void* d_ws, size_t ws_size,
                              hipStream_t stream)
{
    const int N = 50000;
    const int* es = (const int*)d_in[1];
    char* ws = (char*)d_ws;

    // converted bf16 copies of the 19 used float tensors @[0,15MB)
    static const int idxs[19] = {0, 8,9,10,11,12,13,14,15,16, 17,18,19,20,21,22,23,24,25};
    // exp2-prescale: Wih/Whh -> gate = (i>>14)&3 ; bih/bhh -> gate = (i>>7)&3
    static const int gss[19]  = {0, 0,0,14,14,7,7,0,0,0, 0,0,14,14,7,7,0,0,0};
    bf16* conv[19];
    size_t off = 0;
    CvtAll ca;
    for (int k = 0; k < 19; k++) {
        conv[k] = (bf16*)ws + off;
        ca.t[k].src = d_in[idxs[k]];
        ca.t[k].dst = conv[k];
        ca.t[k].n = in_sizes[idxs[k]];
        ca.t[k].gs = gss[k];
        off += (size_t)((in_sizes[idxs[k]] + 63) & ~63);
    }
    int* flag = (int*)(ws + ((size_t)15 << 20));
    bf16* aggr = (bf16*)(ws + ((size_t)16 << 20));   // [N,128]
    bf16* Y    = (bf16*)(ws + ((size_t)30 << 20));   // [N,512] permuted
    bf16* h1   = (bf16*)(ws + ((size_t)84 << 20));   // [N,128]

    const bf16 *xc  = conv[0];
    const bf16 *Wp1 = conv[1],  *bp1 = conv[2],  *Wih1 = conv[3],  *Whh1 = conv[4];
    const bf16 *bih1 = conv[5], *bhh1 = conv[6], *Wl1 = conv[7],   *bl1 = conv[8],  *Wr1 = conv[9];
    const bf16 *Wp2 = conv[10], *bp2 = conv[11], *Wih2 = conv[12], *Whh2 = conv[13];
    const bf16 *bih2 = conv[14], *bhh2 = conv[15], *Wl2 = conv[16], *bl2 = conv[17], *Wr2 = conv[18];

    dim3 blk(256);
    const int gx = (N + 63) / 64;    // 782
    const int gl = N / 16;           // 3125 (exact)

    detect_dtype<<<dim3(1), dim3(64), 0, stream>>>((const unsigned short*)d_in[0], flag);
    convert_inputs<<<dim3(1024), blk, 0, stream>>>(ca, flag);

    // ---- layer 1 ----
    fused_xp_y<<<dim3(gx), blk, 0, stream>>>(xc, Wp1, bp1, Wih1, bih1, bhh1, Y, N);
    lstm_aggr<<<dim3(gl), dim3(512), 0, stream>>>(Y, es, Whh1, aggr, N);

    // ---- between layers: lin1 -> xp2 -> Y2 ----
    fused_lin_xp_y<<<dim3(gx), blk, 0, stream>>>(
        aggr, Wl1, bl1, xc, Wr1, h1, Wp2, bp2, Wih2, bih2, bhh2, Y, N);
    lstm_aggr<<<dim3(gl), dim3(512), 0, stream>>>(Y, es, Whh2, aggr, N);

    // ---- final: out = lin_l2(aggr) + bl2 + lin_r2(h1) ----
    gemm_bias<3, false, false, true, true><<<dim3(gx, 1), blk, 0, stream>>>(
        aggr, Wl2, bl2, nullptr, h1, Wr2, d_out, flag, N, 40, 40);
}

// Round 3
// 678.972 us; speedup vs baseline: 1.0300x; 1.0300x over previous
//
#include <hip/hip_runtime.h>
#include <hip/hip_bf16.h>

// GCN_5016521802361: 2x SAGEConv(aggr='lstm', project=True), N=50000, D=16, F=128, C=40.
// Round 16:
//  - lstm_aggr: revert to r14 DMA+LDS stage pipeline (measured plateau optimum),
//    deepened to 3 buffers with issue-at-top (pair t+2 issued before consuming
//    pair t; vmcnt(2) steady / vmcnt(0) at t=15); t=0 recurrent MFMA skipped.
//  - Producers: tile-lane -> memory-position remap (pos = lid*8+ct instead of
//    ct*16+lid). ydecode(position) unchanged => lstm input bit-identical, but
//    each thread now stores short8 (16B) runs: Y/T/T1/T2/h1 writes vectorized
//    (8x fewer store insts, 128B-contiguous per 16 lanes).
//  - detect_dtype merged into convert_inputs (per-block redundant detect;
//    block 0 publishes flag for gemm_bias); convert vectorized 8-wide.

typedef __hip_bfloat16 bf16;
typedef __attribute__((ext_vector_type(8))) short short8;
typedef __attribute__((ext_vector_type(4))) short short4v;
typedef __attribute__((ext_vector_type(4))) float floatx4;

#define LOG2E 1.4426950408889634f
#define TWOL  2.8853900817779268f

__device__ __forceinline__ float bf2f(bf16 v) { return __bfloat162float(v); }
__device__ __forceinline__ bf16  f2bf(float v) { return __float2bfloat16(v); }
__device__ __forceinline__ float bfs2f(short s) {
    union { float f; unsigned u; } v; v.u = ((unsigned)(unsigned short)s) << 16; return v.f;
}
__device__ __forceinline__ short f2bfs(float v) {
    bf16 b = __float2bfloat16(v); return *(short*)&b;
}

__device__ __forceinline__ float ex2(float x) {
#if __has_builtin(__builtin_amdgcn_exp2f)
    return __builtin_amdgcn_exp2f(x);
#else
    return exp2f(x);
#endif
}

// LSTM cell, prescaled inputs: i_,f_,o_ carry log2e, g_ carries 2*log2e,
// c is tracked as (2*log2e)*c_true. Single merged rcp on the c path.
__device__ __forceinline__ float cell(float i_, float f_, float g_, float o_, float& c) {
    float ei = ex2(-i_), ef = ex2(-f_), eg = ex2(g_), eo = ex2(-o_);
    float A = (1.f + ei) * (eg + 1.f);
    float B = 1.f + ef;
    float cn = fmaf(c, A, fmaf(eg, TWOL, -TWOL) * B) * __builtin_amdgcn_rcpf(A * B);
    c = cn;
    float ec = ex2(cn);
    return (ec - 1.f) * __builtin_amdgcn_rcpf((ec + 1.f) * (1.f + eo));
}

// Permuted-Y memory position p -> source gate row (UNCHANGED map; consumers
// depend only on position->gatecol, not on which producer lane wrote it).
__device__ __forceinline__ int ydecode(int p) {
    int pw = (p >> 6) & 7, pq = (p >> 4) & 3, pg = (p >> 2) & 3, pr = p & 3;
    return pg * 128 + pw * 16 + pq * 4 + pr;
}

// two 16B/lane global->LDS DMAs covering a wave's 2KB slice
__device__ __forceinline__ void dma2(const bf16* gp, void* lp0, void* lp1) {
    __builtin_amdgcn_global_load_lds(
        (const __attribute__((address_space(1))) void*)gp,
        (__attribute__((address_space(3))) void*)lp0, 16, 0, 0);
    __builtin_amdgcn_global_load_lds(
        (const __attribute__((address_space(1))) void*)(gp + 32),
        (__attribute__((address_space(3))) void*)lp1, 16, 0, 0);
}

struct Cvt { const void* src; bf16* dst; int n; int gs; };
struct CvtAll { Cvt t[19]; };

typedef __attribute__((ext_vector_type(4))) float float4v;

// merged dtype-detect + vectorized convert (8 elems/thread/iter)
__global__ void convert_inputs(CvtAll ca, int* __restrict__ flag) {
    __shared__ int sflag;
    // per-block redundant detect on first 1024 u16 of x (deterministic)
    {
        const unsigned short* xb = (const unsigned short*)ca.t[0].src;
        int cnt = 0;
        for (int i = threadIdx.x; i < 1024; i += blockDim.x) {
            int e = (xb[i] >> 7) & 0xFF;
            cnt += (e >= 0xC8);
        }
        if (threadIdx.x == 0) sflag = 0;
        __syncthreads();
        if (cnt) atomicAdd(&sflag, cnt);
        __syncthreads();
    }
    const bool isf32 = (sflag >= 16);
    if (blockIdx.x == 0 && threadIdx.x == 0) *flag = isf32 ? 1 : 0;

    const int stride = gridDim.x * blockDim.x;
    const int tid0 = blockIdx.x * blockDim.x + threadIdx.x;
#pragma unroll 1
    for (int k = 0; k < 19; k++) {
        const int n = ca.t[k].n, gs = ca.t[k].gs;
        const int n8 = n >> 3;
        bf16* d = ca.t[k].dst;
        for (int i = tid0; i < n8; i += stride) {
            const int base = i << 3;
            float m = 1.f;
            if (gs) m = ((((unsigned)base >> gs) & 3) == 2) ? TWOL : LOG2E;
            short8 ov;
            if (isf32) {
                const float4v* sp = (const float4v*)ca.t[k].src;
                float4v a = sp[2 * i], b = sp[2 * i + 1];
#pragma unroll
                for (int j = 0; j < 4; j++) {
                    ov[j]     = f2bfs(a[j] * m);
                    ov[4 + j] = f2bfs(b[j] * m);
                }
            } else {
                short8 sv = ((const short8*)ca.t[k].src)[i];
                if (gs) {
#pragma unroll
                    for (int j = 0; j < 8; j++) ov[j] = f2bfs(bfs2f(sv[j]) * m);
                } else ov = sv;
            }
            ((short8*)d)[i] = ov;
        }
        // scalar tail (n not multiple of 8 — defensive)
        for (int i = (n8 << 3) + tid0; i < n; i += stride) {
            float v = isf32 ? ((const float*)ca.t[k].src)[i]
                            : bfs2f(((const short*)ca.t[k].src)[i]);
            if (gs) v *= ((((unsigned)i >> gs) & 3) == 2) ? TWOL : LOG2E;
            d[i] = f2bf(v);
        }
    }
}

// generic (final lin2 layer)
template <int NCT, bool RELU, bool BIAS2, bool DUAL, bool OUTF>
__global__ __launch_bounds__(256, 2) void gemm_bias(
    const bf16* __restrict__ A, const bf16* __restrict__ B,
    const bf16* __restrict__ bias, const bf16* __restrict__ bias2,
    const bf16* __restrict__ A2, const bf16* __restrict__ B2,
    void* __restrict__ Cv, const int* __restrict__ oflag,
    int N, int nbt, int ldc)
{
    const int tid = threadIdx.x;
    const int w = tid >> 6, l = tid & 63, q = l >> 4, lid = l & 15;
    const int rowbase = blockIdx.x * 64 + w * 16;
    const int colslice = blockIdx.y * (NCT * 16);

    int arow = rowbase + lid;
    if (arow >= N) arow = N - 1;

    floatx4 acc[NCT];
#pragma unroll
    for (int ct = 0; ct < NCT; ct++) acc[ct] = (floatx4)(0.f);

    short8 bfrag[NCT][4];
#pragma unroll
    for (int ct = 0; ct < NCT; ct++) {
        int j = colslice + ct * 16 + lid;
        if (j >= nbt) j = nbt - 1;
#pragma unroll
        for (int kt = 0; kt < 4; kt++)
            bfrag[ct][kt] = *(const short8*)(B + (size_t)j * 128 + kt * 32 + q * 8);
    }
#pragma unroll
    for (int kt = 0; kt < 4; kt++) {
        short8 af = *(const short8*)(A + (size_t)arow * 128 + kt * 32 + q * 8);
#pragma unroll
        for (int ct = 0; ct < NCT; ct++)
            acc[ct] = __builtin_amdgcn_mfma_f32_16x16x32_bf16(af, bfrag[ct][kt], acc[ct], 0, 0, 0);
    }
    if constexpr (DUAL) {
#pragma unroll
        for (int ct = 0; ct < NCT; ct++) {
            int j = colslice + ct * 16 + lid;
            if (j >= nbt) j = nbt - 1;
#pragma unroll
            for (int kt = 0; kt < 4; kt++)
                bfrag[ct][kt] = *(const short8*)(B2 + (size_t)j * 128 + kt * 32 + q * 8);
        }
#pragma unroll
        for (int kt = 0; kt < 4; kt++) {
            short8 af = *(const short8*)(A2 + (size_t)arow * 128 + kt * 32 + q * 8);
#pragma unroll
            for (int ct = 0; ct < NCT; ct++)
                acc[ct] = __builtin_amdgcn_mfma_f32_16x16x32_bf16(af, bfrag[ct][kt], acc[ct], 0, 0, 0);
        }
    }
    bool of32 = false;
    if constexpr (OUTF) of32 = (*oflag != 0);
#pragma unroll
    for (int ct = 0; ct < NCT; ct++) {
        int cg = colslice + ct * 16 + lid;
        int cb = cg < nbt ? cg : nbt - 1;
        float bv = bf2f(bias[cb]);
        if constexpr (BIAS2) bv += bf2f(bias2[cb]);
#pragma unroll
        for (int r = 0; r < 4; r++) {
            int row = rowbase + q * 4 + r;
            float v = acc[ct][r] + bv;
            if constexpr (RELU) v = fmaxf(v, 0.f);
            if (row < N && cg < nbt) {
                size_t idx = (size_t)row * ldc + cg;
                if constexpr (OUTF) {
                    if (of32) ((float*)Cv)[idx] = v;
                    else      ((bf16*)Cv)[idx] = f2bf(v);
                } else {
                    ((bf16*)Cv)[idx] = f2bf(v);
                }
            }
        }
    }
}

// ---------------------------------------------------------------------------
// Fused layer entry: Y = (relu(X@Wp^T+bp)) @ Wih^T + bih + bhh, permuted layout.
// Tile-lane remap: MFMA tile ct's lane lid covers memory position lid*8+ct
// (within the 128-chunk) so each thread's 8 ct-values are position-consecutive
// => short8 stores. ydecode(position) unchanged.
// ---------------------------------------------------------------------------
__global__ __launch_bounds__(256, 2) void fused_xp_y(
    const bf16* __restrict__ X, const bf16* __restrict__ Wp, const bf16* __restrict__ bp,
    const bf16* __restrict__ Wih, const bf16* __restrict__ bih, const bf16* __restrict__ bhh,
    bf16* __restrict__ Yout, int N)
{
    __shared__ bf16 T[64][136];
    const int tid = threadIdx.x;
    const int w = tid >> 6, l = tid & 63, q = l >> 4, lid = l & 15;
    const int rowbase = blockIdx.x * 64;

    int arow = rowbase + w * 16 + lid;
    if (arow >= N) arow = N - 1;

    floatx4 acc[8];
    short8 bfrag[8][4];
    float bvv[8];

    // ---- stage A: xp = relu(X@Wp^T + bp) -> T (cols lid*8+ct) ----
#pragma unroll
    for (int ct = 0; ct < 8; ct++) acc[ct] = (floatx4)(0.f);
#pragma unroll
    for (int ct = 0; ct < 8; ct++) {
        int j = lid * 8 + ct;
        bvv[ct] = bf2f(bp[j]);
#pragma unroll
        for (int kt = 0; kt < 4; kt++)
            bfrag[ct][kt] = *(const short8*)(Wp + (size_t)j * 128 + kt * 32 + q * 8);
    }
#pragma unroll
    for (int kt = 0; kt < 4; kt++) {
        short8 af = *(const short8*)(X + (size_t)arow * 128 + kt * 32 + q * 8);
#pragma unroll
        for (int ct = 0; ct < 8; ct++)
            acc[ct] = __builtin_amdgcn_mfma_f32_16x16x32_bf16(af, bfrag[ct][kt], acc[ct], 0, 0, 0);
    }
#pragma unroll
    for (int r = 0; r < 4; r++) {
        short8 ov;
#pragma unroll
        for (int ct = 0; ct < 8; ct++)
            ov[ct] = f2bfs(fmaxf(acc[ct][r] + bvv[ct], 0.f));
        *(short8*)&T[w * 16 + q * 4 + r][lid * 8] = ov;
    }
    __syncthreads();

    // ---- stage B: Y chunks; positions lid*8+ct; short8 stores ----
#pragma unroll 1
    for (int cc = 0; cc < 4; cc++) {
#pragma unroll
        for (int ct = 0; ct < 8; ct++) {
            int src = ydecode(cc * 128 + lid * 8 + ct);
            bvv[ct] = bf2f(bih[src]) + bf2f(bhh[src]);
#pragma unroll
            for (int kt = 0; kt < 4; kt++)
                bfrag[ct][kt] = *(const short8*)(Wih + (size_t)src * 128 + kt * 32 + q * 8);
        }
#pragma unroll
        for (int ct = 0; ct < 8; ct++) acc[ct] = (floatx4)(0.f);
#pragma unroll
        for (int kt = 0; kt < 4; kt++) {
            short8 af = *(const short8*)&T[w * 16 + lid][kt * 32 + q * 8];
#pragma unroll
            for (int ct = 0; ct < 8; ct++)
                acc[ct] = __builtin_amdgcn_mfma_f32_16x16x32_bf16(af, bfrag[ct][kt], acc[ct], 0, 0, 0);
        }
#pragma unroll
        for (int r = 0; r < 4; r++) {
            int row = rowbase + w * 16 + q * 4 + r;
            if (row < N) {
                short8 ov;
#pragma unroll
                for (int ct = 0; ct < 8; ct++)
                    ov[ct] = f2bfs(acc[ct][r] + bvv[ct]);
                *(short8*)(Yout + (size_t)row * 512 + cc * 128 + lid * 8) = ov;
            }
        }
    }
}

// ---------------------------------------------------------------------------
// Fused between-layers: h1 = relu(aggr@Wl^T+bl+X@Wr^T); xp2 = relu(h1@Wp2^T+bp2);
// Y2 = permuted. All tiles use the lid*8+ct lane remap; vector stores.
// ---------------------------------------------------------------------------
__global__ __launch_bounds__(256, 2) void fused_lin_xp_y(
    const bf16* __restrict__ aggr, const bf16* __restrict__ Wl, const bf16* __restrict__ bl,
    const bf16* __restrict__ X, const bf16* __restrict__ Wr,
    bf16* __restrict__ h1out,
    const bf16* __restrict__ Wp2, const bf16* __restrict__ bp2,
    const bf16* __restrict__ Wih2, const bf16* __restrict__ bih2, const bf16* __restrict__ bhh2,
    bf16* __restrict__ Yout, int N)
{
    __shared__ bf16 T1[64][136];
    __shared__ bf16 T2[64][136];
    const int tid = threadIdx.x;
    const int w = tid >> 6, l = tid & 63, q = l >> 4, lid = l & 15;
    const int rowbase = blockIdx.x * 64;

    int arow = rowbase + w * 16 + lid;
    if (arow >= N) arow = N - 1;

    floatx4 acc[8];
    short8 bfrag[8][4];
    float bvv[8];

    // ---- stage A: h1 ----
#pragma unroll
    for (int ct = 0; ct < 8; ct++) acc[ct] = (floatx4)(0.f);
#pragma unroll
    for (int ct = 0; ct < 8; ct++) {
        int j = lid * 8 + ct;
        bvv[ct] = bf2f(bl[j]);
#pragma unroll
        for (int kt = 0; kt < 4; kt++)
            bfrag[ct][kt] = *(const short8*)(Wl + (size_t)j * 128 + kt * 32 + q * 8);
    }
#pragma unroll
    for (int kt = 0; kt < 4; kt++) {
        short8 af = *(const short8*)(aggr + (size_t)arow * 128 + kt * 32 + q * 8);
#pragma unroll
        for (int ct = 0; ct < 8; ct++)
            acc[ct] = __builtin_amdgcn_mfma_f32_16x16x32_bf16(af, bfrag[ct][kt], acc[ct], 0, 0, 0);
    }
#pragma unroll
    for (int ct = 0; ct < 8; ct++) {
        int j = lid * 8 + ct;
#pragma unroll
        for (int kt = 0; kt < 4; kt++)
            bfrag[ct][kt] = *(const short8*)(Wr + (size_t)j * 128 + kt * 32 + q * 8);
    }
#pragma unroll
    for (int kt = 0; kt < 4; kt++) {
        short8 af = *(const short8*)(X + (size_t)arow * 128 + kt * 32 + q * 8);
#pragma unroll
        for (int ct = 0; ct < 8; ct++)
            acc[ct] = __builtin_amdgcn_mfma_f32_16x16x32_bf16(af, bfrag[ct][kt], acc[ct], 0, 0, 0);
    }
#pragma unroll
    for (int r = 0; r < 4; r++) {
        short8 ov;
#pragma unroll
        for (int ct = 0; ct < 8; ct++)
            ov[ct] = f2bfs(fmaxf(acc[ct][r] + bvv[ct], 0.f));
        int rl = w * 16 + q * 4 + r;
        *(short8*)&T1[rl][lid * 8] = ov;
        int row = rowbase + rl;
        if (row < N) *(short8*)(h1out + (size_t)row * 128 + lid * 8) = ov;
    }
    __syncthreads();

    // ---- stage B: xp2 -> T2 ----
#pragma unroll
    for (int ct = 0; ct < 8; ct++) {
        int j = lid * 8 + ct;
        bvv[ct] = bf2f(bp2[j]);
#pragma unroll
        for (int kt = 0; kt < 4; kt++)
            bfrag[ct][kt] = *(const short8*)(Wp2 + (size_t)j * 128 + kt * 32 + q * 8);
    }
#pragma unroll
    for (int ct = 0; ct < 8; ct++) acc[ct] = (floatx4)(0.f);
#pragma unroll
    for (int kt = 0; kt < 4; kt++) {
        short8 af = *(const short8*)&T1[w * 16 + lid][kt * 32 + q * 8];
#pragma unroll
        for (int ct = 0; ct < 8; ct++)
            acc[ct] = __builtin_amdgcn_mfma_f32_16x16x32_bf16(af, bfrag[ct][kt], acc[ct], 0, 0, 0);
    }
#pragma unroll
    for (int r = 0; r < 4; r++) {
        short8 ov;
#pragma unroll
        for (int ct = 0; ct < 8; ct++)
            ov[ct] = f2bfs(fmaxf(acc[ct][r] + bvv[ct], 0.f));
        *(short8*)&T2[w * 16 + q * 4 + r][lid * 8] = ov;
    }
    __syncthreads();

    // ---- stage C: Y2 chunks ----
#pragma unroll 1
    for (int cc = 0; cc < 4; cc++) {
#pragma unroll
        for (int ct = 0; ct < 8; ct++) {
            int src = ydecode(cc * 128 + lid * 8 + ct);
            bvv[ct] = bf2f(bih2[src]) + bf2f(bhh2[src]);
#pragma unroll
            for (int kt = 0; kt < 4; kt++)
                bfrag[ct][kt] = *(const short8*)(Wih2 + (size_t)src * 128 + kt * 32 + q * 8);
        }
#pragma unroll
        for (int ct = 0; ct < 8; ct++) acc[ct] = (floatx4)(0.f);
#pragma unroll
        for (int kt = 0; kt < 4; kt++) {
            short8 af = *(const short8*)&T2[w * 16 + lid][kt * 32 + q * 8];
#pragma unroll
            for (int ct = 0; ct < 8; ct++)
                acc[ct] = __builtin_amdgcn_mfma_f32_16x16x32_bf16(af, bfrag[ct][kt], acc[ct], 0, 0, 0);
        }
#pragma unroll
        for (int r = 0; r < 4; r++) {
            int row = rowbase + w * 16 + q * 4 + r;
            if (row < N) {
                short8 ov;
#pragma unroll
                for (int ct = 0; ct < 8; ct++)
                    ov[ct] = f2bfs(acc[ct][r] + bvv[ct]);
                *(short8*)(Yout + (size_t)row * 512 + cc * 128 + lid * 8) = ov;
            }
        }
    }
}

// ---------------------------------------------------------------------------
// LSTM neighbor aggregation: r14 wave-private DMA+LDS stage pipeline, deepened
// to 3 buffers. 512 thr / 8 waves / 16 nodes; wave w owns hidden cols
// [16w,16w+16). Per step: wait vmcnt(2) (pair t landed, t+1 in flight), issue
// pair t+2 into buf (t+2)%3 (~2-step slack), consume, MFMA (skipped at t=0),
// cell, hb exchange via lgkmcnt(0)+s_barrier only (no vmcnt drain).
// ---------------------------------------------------------------------------
__global__ __launch_bounds__(512, 4) void lstm_aggr(
    const bf16* __restrict__ Y,     // [N,512] PERMUTED, prescaled pre-activations
    const int* __restrict__ esrc,   // [N,16]
    const bf16* __restrict__ Whh,   // [512,128] prescaled by gate
    bf16* __restrict__ aggr,        // [N,128] out: final h
    int N)
{
    __shared__ alignas(16) short stage[3][8][1024];  // [buf][wave][2KB slice]
    __shared__ alignas(16) bf16 hb[2][16][136];
    __shared__ int srcl[16][16];    // [t][node]

    const int tid = threadIdx.x;
    const int w = tid >> 6, l = tid & 63, q = l >> 4, lid = l & 15;
    const int nodebase = blockIdx.x * 16;   // N = 50000 = 3125*16, exact

    if (tid < 256) {
        int node = tid >> 4, t = tid & 15;
        srcl[t][node] = esrc[(size_t)(nodebase + node) * 16 + t];
    }

    // Whh A-fragments: wf[g][kt]; A-row = gatecol = g*128 + 16*w + lid
    short8 wf[4][4];
#pragma unroll
    for (int g = 0; g < 4; g++) {
        int gc = g * 128 + 16 * w + lid;
#pragma unroll
        for (int kt = 0; kt < 4; kt++)
            wf[g][kt] = *(const short8*)(Whh + (size_t)gc * 128 + kt * 32 + q * 8);
    }

    float c[4];
#pragma unroll
    for (int r = 0; r < 4; r++) c[r] = 0.f;

    // lane l of issue0 fills stage chunk l*16B <- Y[srcl[t][l&15]] elements
    // [w*64 + (l>>4)*8, +8); issue1 = +32 elements, +512 shorts in LDS.
    const int laneoff = w * 64 + q * 8;

    __syncthreads();   // srcl visible before first DMA

    // prologue: pairs 0,1 -> bufs 0,1
    {
        int s0 = srcl[0][lid];
        dma2(Y + (size_t)s0 * 512 + laneoff, &stage[0][w][0], &stage[0][w][512]);
        int s1 = srcl[1][lid];
        dma2(Y + (size_t)s1 * 512 + laneoff, &stage[1][w][0], &stage[1][w][512]);
    }

#pragma unroll
    for (int t = 0; t < 16; t++) {
        const int cb = t % 3;       // stage buffer
        const int hc = t & 1;       // hb buffer

        // pair t landed; pair t+1 stays in flight
        if (t == 15) asm volatile("s_waitcnt vmcnt(0)" ::: "memory");
        else         asm volatile("s_waitcnt vmcnt(2)" ::: "memory");

        // issue pair t+2 into buf (t+2)%3 (freed after step t-1's reads)
        if (t < 14) {
            int sn = srcl[t + 2][lid];
            int nb = (t + 2) % 3;
            dma2(Y + (size_t)sn * 512 + laneoff, &stage[nb][w][0], &stage[nb][w][512]);
        }

        floatx4 acc[4];
        {
            const short* wbuf = &stage[cb][w][0];
            short8 y0 = *(const short8*)&wbuf[q * 256 + lid * 8];
            short8 y1 = *(const short8*)&wbuf[q * 256 + 128 + lid * 8];
#pragma unroll
            for (int g = 0; g < 2; g++)
#pragma unroll
                for (int r = 0; r < 4; r++) {
                    acc[g][r]     = bfs2f(y0[g * 4 + r]);
                    acc[2 + g][r] = bfs2f(y1[g * 4 + r]);
                }
        }

        if (t) {   // h0 = 0: skip recurrent MFMA at t=0
#pragma unroll
            for (int kt = 0; kt < 4; kt++) {
                short8 bh = *(const short8*)&hb[hc][lid][kt * 32 + q * 8];
#pragma unroll
                for (int g = 0; g < 4; g++)
                    acc[g] = __builtin_amdgcn_mfma_f32_16x16x32_bf16(wf[g][kt], bh, acc[g], 0, 0, 0);
            }
        }

        {
            short4v hv;
#pragma unroll
            for (int r = 0; r < 4; r++)
                hv[r] = f2bfs(cell(acc[0][r], acc[1][r], acc[2][r], acc[3][r], c[r]));
            if (t < 15) {
                *(short4v*)&hb[hc ^ 1][lid][16 * w + 4 * q] = hv;
                asm volatile("s_waitcnt lgkmcnt(0)" ::: "memory");
                __builtin_amdgcn_s_barrier();   // hb exchange only — no vmcnt drain
            } else {
                *(short4v*)(aggr + (size_t)(nodebase + lid) * 128 + 16 * w + 4 * q) = hv;
            }
        }
    }
}

extern "C" void kernel_launch(void* const* d_in, const int* in_sizes, int n_in,
                              void* d_out, int out_size, void* d_ws, size_t ws_size,
                              hipStream_t stream)
{
    const int N = 50000;
    const int* es = (const int*)d_in[1];
    char* ws = (char*)d_ws;

    // converted bf16 copies of the 19 used float tensors @[0,15MB)
    static const int idxs[19] = {0, 8,9,10,11,12,13,14,15,16, 17,18,19,20,21,22,23,24,25};
    // exp2-prescale: Wih/Whh -> gate = (i>>14)&3 ; bih/bhh -> gate = (i>>7)&3
    static const int gss[19]  = {0, 0,0,14,14,7,7,0,0,0, 0,0,14,14,7,7,0,0,0};
    bf16* conv[19];
    size_t off = 0;
    CvtAll ca;
    for (int k = 0; k < 19; k++) {
        conv[k] = (bf16*)ws + off;
        ca.t[k].src = d_in[idxs[k]];
        ca.t[k].dst = conv[k];
        ca.t[k].n = in_sizes[idxs[k]];
        ca.t[k].gs = gss[k];
        off += (size_t)((in_sizes[idxs[k]] + 63) & ~63);
    }
    int* flag = (int*)(ws + ((size_t)15 << 20));
    bf16* aggr = (bf16*)(ws + ((size_t)16 << 20));   // [N,128]
    bf16* Y    = (bf16*)(ws + ((size_t)30 << 20));   // [N,512] permuted
    bf16* h1   = (bf16*)(ws + ((size_t)84 << 20));   // [N,128]

    const bf16 *xc  = conv[0];
    const bf16 *Wp1 = conv[1],  *bp1 = conv[2],  *Wih1 = conv[3],  *Whh1 = conv[4];
    const bf16 *bih1 = conv[5], *bhh1 = conv[6], *Wl1 = conv[7],   *bl1 = conv[8],  *Wr1 = conv[9];
    const bf16 *Wp2 = conv[10], *bp2 = conv[11], *Wih2 = conv[12], *Whh2 = conv[13];
    const bf16 *bih2 = conv[14], *bhh2 = conv[15], *Wl2 = conv[16], *bl2 = conv[17], *Wr2 = conv[18];

    dim3 blk(256);
    const int gx = (N + 63) / 64;    // 782
    const int gl = N / 16;           // 3125 (exact)

    convert_inputs<<<dim3(1024), blk, 0, stream>>>(ca, flag);

    // ---- layer 1 ----
    fused_xp_y<<<dim3(gx), blk, 0, stream>>>(xc, Wp1, bp1, Wih1, bih1, bhh1, Y, N);
    lstm_aggr<<<dim3(gl), dim3(512), 0, stream>>>(Y, es, Whh1, aggr, N);

    // ---- between layers: lin1 -> xp2 -> Y2 ----
    fused_lin_xp_y<<<dim3(gx), blk, 0, stream>>>(
        aggr, Wl1, bl1, xc, Wr1, h1, Wp2, bp2, Wih2, bih2, bhh2, Y, N);
    lstm_aggr<<<dim3(gl), dim3(512), 0, stream>>>(Y, es, Whh2, aggr, N);

    // ---- final: out = lin_l2(aggr) + bl2 + lin_r2(h1) ----
    gemm_bias<3, false, false, true, true><<<dim3(gx, 1), blk, 0, stream>>>(
        aggr, Wl2, bl2, nullptr, h1, Wr2, d_out, flag, N, 40, 40);
}

// Round 4
// 670.737 us; speedup vs baseline: 1.0426x; 1.0123x over previous
//
#include <hip/hip_runtime.h>
#include <hip/hip_bf16.h>

// GCN_5016521802361: 2x SAGEConv(aggr='lstm', project=True), N=50000, D=16, F=128, C=40.
// Round 17: consolidation. lstm_aggr reverted to the r14-exact measured optimum
// (195.6 us: 2-buffer wave-private DMA stage, issue-after-cell in the barrier
// shadow, counted vmcnt(2), t=0 MFMA skip). Producers keep the r16 wins:
// tile-lane->memory-position remap (pos = lid*8+ct) for short8 vector stores on
// Y/T/T1/T2/h1 (ydecode unchanged => lstm input bit-identical), merged
// dtype-detect + 8-wide vectorized convert.

typedef __hip_bfloat16 bf16;
typedef __attribute__((ext_vector_type(8))) short short8;
typedef __attribute__((ext_vector_type(4))) short short4v;
typedef __attribute__((ext_vector_type(4))) float floatx4;

#define LOG2E 1.4426950408889634f
#define TWOL  2.8853900817779268f

__device__ __forceinline__ float bf2f(bf16 v) { return __bfloat162float(v); }
__device__ __forceinline__ bf16  f2bf(float v) { return __float2bfloat16(v); }
__device__ __forceinline__ float bfs2f(short s) {
    union { float f; unsigned u; } v; v.u = ((unsigned)(unsigned short)s) << 16; return v.f;
}
__device__ __forceinline__ short f2bfs(float v) {
    bf16 b = __float2bfloat16(v); return *(short*)&b;
}

__device__ __forceinline__ float ex2(float x) {
#if __has_builtin(__builtin_amdgcn_exp2f)
    return __builtin_amdgcn_exp2f(x);
#else
    return exp2f(x);
#endif
}

// LSTM cell, prescaled inputs: i_,f_,o_ carry log2e, g_ carries 2*log2e,
// c is tracked as (2*log2e)*c_true. Single merged rcp on the c path.
__device__ __forceinline__ float cell(float i_, float f_, float g_, float o_, float& c) {
    float ei = ex2(-i_), ef = ex2(-f_), eg = ex2(g_), eo = ex2(-o_);
    float A = (1.f + ei) * (eg + 1.f);
    float B = 1.f + ef;
    float cn = fmaf(c, A, fmaf(eg, TWOL, -TWOL) * B) * __builtin_amdgcn_rcpf(A * B);
    c = cn;
    float ec = ex2(cn);
    return (ec - 1.f) * __builtin_amdgcn_rcpf((ec + 1.f) * (1.f + eo));
}

// Permuted-Y memory position p -> source gate row (consumers depend only on
// position->gatecol; which producer lane writes it is free to choose).
__device__ __forceinline__ int ydecode(int p) {
    int pw = (p >> 6) & 7, pq = (p >> 4) & 3, pg = (p >> 2) & 3, pr = p & 3;
    return pg * 128 + pw * 16 + pq * 4 + pr;
}

// two 16B/lane global->LDS DMAs covering a wave's 2KB slice
__device__ __forceinline__ void dma2(const bf16* gp, void* lp0, void* lp1) {
    __builtin_amdgcn_global_load_lds(
        (const __attribute__((address_space(1))) void*)gp,
        (__attribute__((address_space(3))) void*)lp0, 16, 0, 0);
    __builtin_amdgcn_global_load_lds(
        (const __attribute__((address_space(1))) void*)(gp + 32),
        (__attribute__((address_space(3))) void*)lp1, 16, 0, 0);
}

struct Cvt { const void* src; bf16* dst; int n; int gs; };
struct CvtAll { Cvt t[19]; };

typedef __attribute__((ext_vector_type(4))) float float4v;

// merged dtype-detect + vectorized convert (8 elems/thread/iter)
__global__ void convert_inputs(CvtAll ca, int* __restrict__ flag) {
    __shared__ int sflag;
    // per-block redundant detect on first 1024 u16 of x (deterministic)
    {
        const unsigned short* xb = (const unsigned short*)ca.t[0].src;
        int cnt = 0;
        for (int i = threadIdx.x; i < 1024; i += blockDim.x) {
            int e = (xb[i] >> 7) & 0xFF;
            cnt += (e >= 0xC8);
        }
        if (threadIdx.x == 0) sflag = 0;
        __syncthreads();
        if (cnt) atomicAdd(&sflag, cnt);
        __syncthreads();
    }
    const bool isf32 = (sflag >= 16);
    if (blockIdx.x == 0 && threadIdx.x == 0) *flag = isf32 ? 1 : 0;

    const int stride = gridDim.x * blockDim.x;
    const int tid0 = blockIdx.x * blockDim.x + threadIdx.x;
#pragma unroll 1
    for (int k = 0; k < 19; k++) {
        const int n = ca.t[k].n, gs = ca.t[k].gs;
        const int n8 = n >> 3;
        bf16* d = ca.t[k].dst;
        for (int i = tid0; i < n8; i += stride) {
            const int base = i << 3;
            float m = 1.f;
            if (gs) m = ((((unsigned)base >> gs) & 3) == 2) ? TWOL : LOG2E;
            short8 ov;
            if (isf32) {
                const float4v* sp = (const float4v*)ca.t[k].src;
                float4v a = sp[2 * i], b = sp[2 * i + 1];
#pragma unroll
                for (int j = 0; j < 4; j++) {
                    ov[j]     = f2bfs(a[j] * m);
                    ov[4 + j] = f2bfs(b[j] * m);
                }
            } else {
                short8 sv = ((const short8*)ca.t[k].src)[i];
                if (gs) {
#pragma unroll
                    for (int j = 0; j < 8; j++) ov[j] = f2bfs(bfs2f(sv[j]) * m);
                } else ov = sv;
            }
            ((short8*)d)[i] = ov;
        }
        // scalar tail (n not multiple of 8 — defensive)
        for (int i = (n8 << 3) + tid0; i < n; i += stride) {
            float v = isf32 ? ((const float*)ca.t[k].src)[i]
                            : bfs2f(((const short*)ca.t[k].src)[i]);
            if (gs) v *= ((((unsigned)i >> gs) & 3) == 2) ? TWOL : LOG2E;
            d[i] = f2bf(v);
        }
    }
}

// generic (final lin2 layer)
template <int NCT, bool RELU, bool BIAS2, bool DUAL, bool OUTF>
__global__ __launch_bounds__(256, 2) void gemm_bias(
    const bf16* __restrict__ A, const bf16* __restrict__ B,
    const bf16* __restrict__ bias, const bf16* __restrict__ bias2,
    const bf16* __restrict__ A2, const bf16* __restrict__ B2,
    void* __restrict__ Cv, const int* __restrict__ oflag,
    int N, int nbt, int ldc)
{
    const int tid = threadIdx.x;
    const int w = tid >> 6, l = tid & 63, q = l >> 4, lid = l & 15;
    const int rowbase = blockIdx.x * 64 + w * 16;
    const int colslice = blockIdx.y * (NCT * 16);

    int arow = rowbase + lid;
    if (arow >= N) arow = N - 1;

    floatx4 acc[NCT];
#pragma unroll
    for (int ct = 0; ct < NCT; ct++) acc[ct] = (floatx4)(0.f);

    short8 bfrag[NCT][4];
#pragma unroll
    for (int ct = 0; ct < NCT; ct++) {
        int j = colslice + ct * 16 + lid;
        if (j >= nbt) j = nbt - 1;
#pragma unroll
        for (int kt = 0; kt < 4; kt++)
            bfrag[ct][kt] = *(const short8*)(B + (size_t)j * 128 + kt * 32 + q * 8);
    }
#pragma unroll
    for (int kt = 0; kt < 4; kt++) {
        short8 af = *(const short8*)(A + (size_t)arow * 128 + kt * 32 + q * 8);
#pragma unroll
        for (int ct = 0; ct < NCT; ct++)
            acc[ct] = __builtin_amdgcn_mfma_f32_16x16x32_bf16(af, bfrag[ct][kt], acc[ct], 0, 0, 0);
    }
    if constexpr (DUAL) {
#pragma unroll
        for (int ct = 0; ct < NCT; ct++) {
            int j = colslice + ct * 16 + lid;
            if (j >= nbt) j = nbt - 1;
#pragma unroll
            for (int kt = 0; kt < 4; kt++)
                bfrag[ct][kt] = *(const short8*)(B2 + (size_t)j * 128 + kt * 32 + q * 8);
        }
#pragma unroll
        for (int kt = 0; kt < 4; kt++) {
            short8 af = *(const short8*)(A2 + (size_t)arow * 128 + kt * 32 + q * 8);
#pragma unroll
            for (int ct = 0; ct < NCT; ct++)
                acc[ct] = __builtin_amdgcn_mfma_f32_16x16x32_bf16(af, bfrag[ct][kt], acc[ct], 0, 0, 0);
        }
    }
    bool of32 = false;
    if constexpr (OUTF) of32 = (*oflag != 0);
#pragma unroll
    for (int ct = 0; ct < NCT; ct++) {
        int cg = colslice + ct * 16 + lid;
        int cb = cg < nbt ? cg : nbt - 1;
        float bv = bf2f(bias[cb]);
        if constexpr (BIAS2) bv += bf2f(bias2[cb]);
#pragma unroll
        for (int r = 0; r < 4; r++) {
            int row = rowbase + q * 4 + r;
            float v = acc[ct][r] + bv;
            if constexpr (RELU) v = fmaxf(v, 0.f);
            if (row < N && cg < nbt) {
                size_t idx = (size_t)row * ldc + cg;
                if constexpr (OUTF) {
                    if (of32) ((float*)Cv)[idx] = v;
                    else      ((bf16*)Cv)[idx] = f2bf(v);
                } else {
                    ((bf16*)Cv)[idx] = f2bf(v);
                }
            }
        }
    }
}

// ---------------------------------------------------------------------------
// Fused layer entry: Y = (relu(X@Wp^T+bp)) @ Wih^T + bih + bhh, permuted layout.
// Tile-lane remap: MFMA tile ct's lane lid covers memory position lid*8+ct
// (within the 128-chunk) so each thread's 8 ct-values are position-consecutive
// => short8 stores. ydecode(position) unchanged.
// ---------------------------------------------------------------------------
__global__ __launch_bounds__(256, 2) void fused_xp_y(
    const bf16* __restrict__ X, const bf16* __restrict__ Wp, const bf16* __restrict__ bp,
    const bf16* __restrict__ Wih, const bf16* __restrict__ bih, const bf16* __restrict__ bhh,
    bf16* __restrict__ Yout, int N)
{
    __shared__ bf16 T[64][136];
    const int tid = threadIdx.x;
    const int w = tid >> 6, l = tid & 63, q = l >> 4, lid = l & 15;
    const int rowbase = blockIdx.x * 64;

    int arow = rowbase + w * 16 + lid;
    if (arow >= N) arow = N - 1;

    floatx4 acc[8];
    short8 bfrag[8][4];
    float bvv[8];

    // ---- stage A: xp = relu(X@Wp^T + bp) -> T (cols lid*8+ct) ----
#pragma unroll
    for (int ct = 0; ct < 8; ct++) acc[ct] = (floatx4)(0.f);
#pragma unroll
    for (int ct = 0; ct < 8; ct++) {
        int j = lid * 8 + ct;
        bvv[ct] = bf2f(bp[j]);
#pragma unroll
        for (int kt = 0; kt < 4; kt++)
            bfrag[ct][kt] = *(const short8*)(Wp + (size_t)j * 128 + kt * 32 + q * 8);
    }
#pragma unroll
    for (int kt = 0; kt < 4; kt++) {
        short8 af = *(const short8*)(X + (size_t)arow * 128 + kt * 32 + q * 8);
#pragma unroll
        for (int ct = 0; ct < 8; ct++)
            acc[ct] = __builtin_amdgcn_mfma_f32_16x16x32_bf16(af, bfrag[ct][kt], acc[ct], 0, 0, 0);
    }
#pragma unroll
    for (int r = 0; r < 4; r++) {
        short8 ov;
#pragma unroll
        for (int ct = 0; ct < 8; ct++)
            ov[ct] = f2bfs(fmaxf(acc[ct][r] + bvv[ct], 0.f));
        *(short8*)&T[w * 16 + q * 4 + r][lid * 8] = ov;
    }
    __syncthreads();

    // ---- stage B: Y chunks; positions lid*8+ct; short8 stores ----
#pragma unroll 1
    for (int cc = 0; cc < 4; cc++) {
#pragma unroll
        for (int ct = 0; ct < 8; ct++) {
            int src = ydecode(cc * 128 + lid * 8 + ct);
            bvv[ct] = bf2f(bih[src]) + bf2f(bhh[src]);
#pragma unroll
            for (int kt = 0; kt < 4; kt++)
                bfrag[ct][kt] = *(const short8*)(Wih + (size_t)src * 128 + kt * 32 + q * 8);
        }
#pragma unroll
        for (int ct = 0; ct < 8; ct++) acc[ct] = (floatx4)(0.f);
#pragma unroll
        for (int kt = 0; kt < 4; kt++) {
            short8 af = *(const short8*)&T[w * 16 + lid][kt * 32 + q * 8];
#pragma unroll
            for (int ct = 0; ct < 8; ct++)
                acc[ct] = __builtin_amdgcn_mfma_f32_16x16x32_bf16(af, bfrag[ct][kt], acc[ct], 0, 0, 0);
        }
#pragma unroll
        for (int r = 0; r < 4; r++) {
            int row = rowbase + w * 16 + q * 4 + r;
            if (row < N) {
                short8 ov;
#pragma unroll
                for (int ct = 0; ct < 8; ct++)
                    ov[ct] = f2bfs(acc[ct][r] + bvv[ct]);
                *(short8*)(Yout + (size_t)row * 512 + cc * 128 + lid * 8) = ov;
            }
        }
    }
}

// ---------------------------------------------------------------------------
// Fused between-layers: h1 = relu(aggr@Wl^T+bl+X@Wr^T); xp2 = relu(h1@Wp2^T+bp2);
// Y2 = permuted. All tiles use the lid*8+ct lane remap; vector stores.
// ---------------------------------------------------------------------------
__global__ __launch_bounds__(256, 2) void fused_lin_xp_y(
    const bf16* __restrict__ aggr, const bf16* __restrict__ Wl, const bf16* __restrict__ bl,
    const bf16* __restrict__ X, const bf16* __restrict__ Wr,
    bf16* __restrict__ h1out,
    const bf16* __restrict__ Wp2, const bf16* __restrict__ bp2,
    const bf16* __restrict__ Wih2, const bf16* __restrict__ bih2, const bf16* __restrict__ bhh2,
    bf16* __restrict__ Yout, int N)
{
    __shared__ bf16 T1[64][136];
    __shared__ bf16 T2[64][136];
    const int tid = threadIdx.x;
    const int w = tid >> 6, l = tid & 63, q = l >> 4, lid = l & 15;
    const int rowbase = blockIdx.x * 64;

    int arow = rowbase + w * 16 + lid;
    if (arow >= N) arow = N - 1;

    floatx4 acc[8];
    short8 bfrag[8][4];
    float bvv[8];

    // ---- stage A: h1 ----
#pragma unroll
    for (int ct = 0; ct < 8; ct++) acc[ct] = (floatx4)(0.f);
#pragma unroll
    for (int ct = 0; ct < 8; ct++) {
        int j = lid * 8 + ct;
        bvv[ct] = bf2f(bl[j]);
#pragma unroll
        for (int kt = 0; kt < 4; kt++)
            bfrag[ct][kt] = *(const short8*)(Wl + (size_t)j * 128 + kt * 32 + q * 8);
    }
#pragma unroll
    for (int kt = 0; kt < 4; kt++) {
        short8 af = *(const short8*)(aggr + (size_t)arow * 128 + kt * 32 + q * 8);
#pragma unroll
        for (int ct = 0; ct < 8; ct++)
            acc[ct] = __builtin_amdgcn_mfma_f32_16x16x32_bf16(af, bfrag[ct][kt], acc[ct], 0, 0, 0);
    }
#pragma unroll
    for (int ct = 0; ct < 8; ct++) {
        int j = lid * 8 + ct;
#pragma unroll
        for (int kt = 0; kt < 4; kt++)
            bfrag[ct][kt] = *(const short8*)(Wr + (size_t)j * 128 + kt * 32 + q * 8);
    }
#pragma unroll
    for (int kt = 0; kt < 4; kt++) {
        short8 af = *(const short8*)(X + (size_t)arow * 128 + kt * 32 + q * 8);
#pragma unroll
        for (int ct = 0; ct < 8; ct++)
            acc[ct] = __builtin_amdgcn_mfma_f32_16x16x32_bf16(af, bfrag[ct][kt], acc[ct], 0, 0, 0);
    }
#pragma unroll
    for (int r = 0; r < 4; r++) {
        short8 ov;
#pragma unroll
        for (int ct = 0; ct < 8; ct++)
            ov[ct] = f2bfs(fmaxf(acc[ct][r] + bvv[ct], 0.f));
        int rl = w * 16 + q * 4 + r;
        *(short8*)&T1[rl][lid * 8] = ov;
        int row = rowbase + rl;
        if (row < N) *(short8*)(h1out + (size_t)row * 128 + lid * 8) = ov;
    }
    __syncthreads();

    // ---- stage B: xp2 -> T2 ----
#pragma unroll
    for (int ct = 0; ct < 8; ct++) {
        int j = lid * 8 + ct;
        bvv[ct] = bf2f(bp2[j]);
#pragma unroll
        for (int kt = 0; kt < 4; kt++)
            bfrag[ct][kt] = *(const short8*)(Wp2 + (size_t)j * 128 + kt * 32 + q * 8);
    }
#pragma unroll
    for (int ct = 0; ct < 8; ct++) acc[ct] = (floatx4)(0.f);
#pragma unroll
    for (int kt = 0; kt < 4; kt++) {
        short8 af = *(const short8*)&T1[w * 16 + lid][kt * 32 + q * 8];
#pragma unroll
        for (int ct = 0; ct < 8; ct++)
            acc[ct] = __builtin_amdgcn_mfma_f32_16x16x32_bf16(af, bfrag[ct][kt], acc[ct], 0, 0, 0);
    }
#pragma unroll
    for (int r = 0; r < 4; r++) {
        short8 ov;
#pragma unroll
        for (int ct = 0; ct < 8; ct++)
            ov[ct] = f2bfs(fmaxf(acc[ct][r] + bvv[ct], 0.f));
        *(short8*)&T2[w * 16 + q * 4 + r][lid * 8] = ov;
    }
    __syncthreads();

    // ---- stage C: Y2 chunks ----
#pragma unroll 1
    for (int cc = 0; cc < 4; cc++) {
#pragma unroll
        for (int ct = 0; ct < 8; ct++) {
            int src = ydecode(cc * 128 + lid * 8 + ct);
            bvv[ct] = bf2f(bih2[src]) + bf2f(bhh2[src]);
#pragma unroll
            for (int kt = 0; kt < 4; kt++)
                bfrag[ct][kt] = *(const short8*)(Wih2 + (size_t)src * 128 + kt * 32 + q * 8);
        }
#pragma unroll
        for (int ct = 0; ct < 8; ct++) acc[ct] = (floatx4)(0.f);
#pragma unroll
        for (int kt = 0; kt < 4; kt++) {
            short8 af = *(const short8*)&T2[w * 16 + lid][kt * 32 + q * 8];
#pragma unroll
            for (int ct = 0; ct < 8; ct++)
                acc[ct] = __builtin_amdgcn_mfma_f32_16x16x32_bf16(af, bfrag[ct][kt], acc[ct], 0, 0, 0);
        }
#pragma unroll
        for (int r = 0; r < 4; r++) {
            int row = rowbase + w * 16 + q * 4 + r;
            if (row < N) {
                short8 ov;
#pragma unroll
                for (int ct = 0; ct < 8; ct++)
                    ov[ct] = f2bfs(acc[ct][r] + bvv[ct]);
                *(short8*)(Yout + (size_t)row * 512 + cc * 128 + lid * 8) = ov;
            }
        }
    }
}

// ---------------------------------------------------------------------------
// LSTM neighbor aggregation (r14-exact: the measured plateau optimum, 195.6us).
// 512 thr / 8 waves / 16 nodes. Wave-private stage slices: wave w DMAs only the
// 128B/row slice it reads (per-lane swizzled global src, linear LDS dest).
// 2-deep pipeline, counted vmcnt(2) at point-of-use; next pair issued AFTER the
// cell (in the barrier-wait shadow); per-step sync = lgkmcnt(0)+s_barrier only.
// t=0 recurrent MFMA skipped (h0=0).
// ---------------------------------------------------------------------------
__global__ __launch_bounds__(512, 4) void lstm_aggr(
    const bf16* __restrict__ Y,     // [N,512] PERMUTED, prescaled pre-activations
    const int* __restrict__ esrc,   // [N,16]
    const bf16* __restrict__ Whh,   // [512,128] prescaled by gate
    bf16* __restrict__ aggr,        // [N,128] out: final h
    int N)
{
    __shared__ alignas(16) short stage[2][8][1024];  // [buf][wave][2KB slice]
    __shared__ alignas(16) bf16 hb[2][16][136];
    __shared__ int srcl[16][16];    // [t][node]

    const int tid = threadIdx.x;
    const int w = tid >> 6, l = tid & 63, q = l >> 4, lid = l & 15;
    const int nodebase = blockIdx.x * 16;   // N = 50000 = 3125*16, exact

    if (tid < 256) {
        int node = tid >> 4, t = tid & 15;
        srcl[t][node] = esrc[(size_t)(nodebase + node) * 16 + t];
    }

    // Whh A-fragments: wf[g][kt]; A-row = gatecol = g*128 + 16*w + lid
    short8 wf[4][4];
#pragma unroll
    for (int g = 0; g < 4; g++) {
        int gc = g * 128 + 16 * w + lid;
#pragma unroll
        for (int kt = 0; kt < 4; kt++)
            wf[g][kt] = *(const short8*)(Whh + (size_t)gc * 128 + kt * 32 + q * 8);
    }

    float c[4];
#pragma unroll
    for (int r = 0; r < 4; r++) c[r] = 0.f;

    // lane l fills stage chunk l*16B <- Y[srcl[t][l&15]] elements
    // [w*64 + (l>>4)*8, +8); second issue = +32 elements (+512 shorts).
    const int laneoff = w * 64 + q * 8;

    __syncthreads();   // srcl visible before first DMA

    // prologue: pairs 0,1 -> bufs 0,1 (oldest-first)
    {
        int s0 = srcl[0][lid];
        dma2(Y + (size_t)s0 * 512 + laneoff, &stage[0][w][0], &stage[0][w][512]);
        int s1 = srcl[1][lid];
        dma2(Y + (size_t)s1 * 512 + laneoff, &stage[1][w][0], &stage[1][w][512]);
    }

#pragma unroll 2
    for (int t = 0; t < 16; t++) {
        const int cb = t & 1;

        // own slice for step t landed; keep the t+1 pair in flight
        if (t == 15) asm volatile("s_waitcnt vmcnt(0)" ::: "memory");
        else         asm volatile("s_waitcnt vmcnt(2)" ::: "memory");

        int snext = (t < 14) ? srcl[t + 2][lid] : 0;

        floatx4 acc[4];
        {
            const short* wbuf = &stage[cb][w][0];
            short8 y0 = *(const short8*)&wbuf[q * 256 + lid * 8];
            short8 y1 = *(const short8*)&wbuf[q * 256 + 128 + lid * 8];
#pragma unroll
            for (int g = 0; g < 2; g++)
#pragma unroll
                for (int r = 0; r < 4; r++) {
                    acc[g][r]     = bfs2f(y0[g * 4 + r]);
                    acc[2 + g][r] = bfs2f(y1[g * 4 + r]);
                }
        }

        if (t) {   // h0 = 0: skip recurrent MFMA at t=0
#pragma unroll
            for (int kt = 0; kt < 4; kt++) {
                short8 bh = *(const short8*)&hb[cb][lid][kt * 32 + q * 8];
#pragma unroll
                for (int g = 0; g < 4; g++)
                    acc[g] = __builtin_amdgcn_mfma_f32_16x16x32_bf16(wf[g][kt], bh, acc[g], 0, 0, 0);
            }
        }

        {
            short4v hv;
#pragma unroll
            for (int r = 0; r < 4; r++)
                hv[r] = f2bfs(cell(acc[0][r], acc[1][r], acc[2][r], acc[3][r], c[r]));
            if (t < 15) *(short4v*)&hb[cb ^ 1][lid][16 * w + 4 * q] = hv;
            else        *(short4v*)(aggr + (size_t)(nodebase + lid) * 128 + 16 * w + 4 * q) = hv;
        }

        if (t < 15) {
            // my stage[cb] reads + hb write retired; stage[cb] free to refill
            asm volatile("s_waitcnt lgkmcnt(0)" ::: "memory");
            if (t < 14)
                dma2(Y + (size_t)snext * 512 + laneoff, &stage[cb][w][0], &stage[cb][w][512]);
            __builtin_amdgcn_s_barrier();   // hb exchange only — no vmcnt drain
        }
    }
}

extern "C" void kernel_launch(void* const* d_in, const int* in_sizes, int n_in,
                              void* d_out, int out_size, void* d_ws, size_t ws_size,
                              hipStream_t stream)
{
    const int N = 50000;
    const int* es = (const int*)d_in[1];
    char* ws = (char*)d_ws;

    // converted bf16 copies of the 19 used float tensors @[0,15MB)
    static const int idxs[19] = {0, 8,9,10,11,12,13,14,15,16, 17,18,19,20,21,22,23,24,25};
    // exp2-prescale: Wih/Whh -> gate = (i>>14)&3 ; bih/bhh -> gate = (i>>7)&3
    static const int gss[19]  = {0, 0,0,14,14,7,7,0,0,0, 0,0,14,14,7,7,0,0,0};
    bf16* conv[19];
    size_t off = 0;
    CvtAll ca;
    for (int k = 0; k < 19; k++) {
        conv[k] = (bf16*)ws + off;
        ca.t[k].src = d_in[idxs[k]];
        ca.t[k].dst = conv[k];
        ca.t[k].n = in_sizes[idxs[k]];
        ca.t[k].gs = gss[k];
        off += (size_t)((in_sizes[idxs[k]] + 63) & ~63);
    }
    int* flag = (int*)(ws + ((size_t)15 << 20));
    bf16* aggr = (bf16*)(ws + ((size_t)16 << 20));   // [N,128]
    bf16* Y    = (bf16*)(ws + ((size_t)30 << 20));   // [N,512] permuted
    bf16* h1   = (bf16*)(ws + ((size_t)84 << 20));   // [N,128]

    const bf16 *xc  = conv[0];
    const bf16 *Wp1 = conv[1],  *bp1 = conv[2],  *Wih1 = conv[3],  *Whh1 = conv[4];
    const bf16 *bih1 = conv[5], *bhh1 = conv[6], *Wl1 = conv[7],   *bl1 = conv[8],  *Wr1 = conv[9];
    const bf16 *Wp2 = conv[10], *bp2 = conv[11], *Wih2 = conv[12], *Whh2 = conv[13];
    const bf16 *bih2 = conv[14], *bhh2 = conv[15], *Wl2 = conv[16], *bl2 = conv[17], *Wr2 = conv[18];

    dim3 blk(256);
    const int gx = (N + 63) / 64;    // 782
    const int gl = N / 16;           // 3125 (exact)

    convert_inputs<<<dim3(1024), blk, 0, stream>>>(ca, flag);

    // ---- layer 1 ----
    fused_xp_y<<<dim3(gx), blk, 0, stream>>>(xc, Wp1, bp1, Wih1, bih1, bhh1, Y, N);
    lstm_aggr<<<dim3(gl), dim3(512), 0, stream>>>(Y, es, Whh1, aggr, N);

    // ---- between layers: lin1 -> xp2 -> Y2 ----
    fused_lin_xp_y<<<dim3(gx), blk, 0, stream>>>(
        aggr, Wl1, bl1, xc, Wr1, h1, Wp2, bp2, Wih2, bih2, bhh2, Y, N);
    lstm_aggr<<<dim3(gl), dim3(512), 0, stream>>>(Y, es, Whh2, aggr, N);

    // ---- final: out = lin_l2(aggr) + bl2 + lin_r2(h1) ----
    gemm_bias<3, false, false, true, true><<<dim3(gx, 1), blk, 0, stream>>>(
        aggr, Wl2, bl2, nullptr, h1, Wr2, d_out, flag, N, 40, 40);
}

// Round 5
// 655.534 us; speedup vs baseline: 1.0668x; 1.0232x over previous
//
#include <hip/hip_runtime.h>
#include <hip/hip_bf16.h>

// GCN_5016521802361: 2x SAGEConv(aggr='lstm', project=True), N=50000, D=16, F=128, C=40.
// Round 18:
//  - gemm_bias fused into lstm2 epilogue (template<EPI>): at t=15 h stays in hb
//    LDS; waves 0-2 compute out[16][40] = h@Wl2^T + bl2 + h1@Wr2^T (rows are the
//    block's own 16 nodes; h1 rows contiguous). Kills 1 kernel + aggr roundtrip.
//  - Wih pre-permuted at convert time (Wihp[pos] = Wih[ydecode(pos)]*gate_scale):
//    producer stage B/C weight rows now LINEAR (pos = cc*128+lid*8+ct) - no
//    ydecode in hot loops, 8-row-contiguous L1 runs per lane.
//  - bias pairs pre-summed to f32 at convert: bsum[pos] = (bih+bhh)[ydecode]*scale.
//  - lstm core unchanged (r14/r17 plateau optimum, 194.6us measured).

typedef __hip_bfloat16 bf16;
typedef __attribute__((ext_vector_type(8))) short short8;
typedef __attribute__((ext_vector_type(4))) short short4v;
typedef __attribute__((ext_vector_type(4))) float floatx4;
typedef __attribute__((ext_vector_type(4))) float float4v;

#define LOG2E 1.4426950408889634f
#define TWOL  2.8853900817779268f

__device__ __forceinline__ float bf2f(bf16 v) { return __bfloat162float(v); }
__device__ __forceinline__ bf16  f2bf(float v) { return __float2bfloat16(v); }
__device__ __forceinline__ float bfs2f(short s) {
    union { float f; unsigned u; } v; v.u = ((unsigned)(unsigned short)s) << 16; return v.f;
}
__device__ __forceinline__ short f2bfs(float v) {
    bf16 b = __float2bfloat16(v); return *(short*)&b;
}

__device__ __forceinline__ float ex2(float x) {
#if __has_builtin(__builtin_amdgcn_exp2f)
    return __builtin_amdgcn_exp2f(x);
#else
    return exp2f(x);
#endif
}

// LSTM cell, prescaled inputs: i_,f_,o_ carry log2e, g_ carries 2*log2e,
// c is tracked as (2*log2e)*c_true. Single merged rcp on the c path.
__device__ __forceinline__ float cell(float i_, float f_, float g_, float o_, float& c) {
    float ei = ex2(-i_), ef = ex2(-f_), eg = ex2(g_), eo = ex2(-o_);
    float A = (1.f + ei) * (eg + 1.f);
    float B = 1.f + ef;
    float cn = fmaf(c, A, fmaf(eg, TWOL, -TWOL) * B) * __builtin_amdgcn_rcpf(A * B);
    c = cn;
    float ec = ex2(cn);
    return (ec - 1.f) * __builtin_amdgcn_rcpf((ec + 1.f) * (1.f + eo));
}

// Permuted-Y memory position p -> source gate row. Used only at convert time now.
__device__ __forceinline__ int ydecode(int p) {
    int pw = (p >> 6) & 7, pq = (p >> 4) & 3, pg = (p >> 2) & 3, pr = p & 3;
    return pg * 128 + pw * 16 + pq * 4 + pr;
}

// two 16B/lane global->LDS DMAs covering a wave's 2KB slice
__device__ __forceinline__ void dma2(const bf16* gp, void* lp0, void* lp1) {
    __builtin_amdgcn_global_load_lds(
        (const __attribute__((address_space(1))) void*)gp,
        (__attribute__((address_space(3))) void*)lp0, 16, 0, 0);
    __builtin_amdgcn_global_load_lds(
        (const __attribute__((address_space(1))) void*)(gp + 32),
        (__attribute__((address_space(3))) void*)lp1, 16, 0, 0);
}

// mode 0: plain copy; mode 1: Whh gate-scale (gate=(elem>>14)&3);
// mode 2: Wih permute+scale (row=elem>>7 is DEST pos-row, src row=ydecode(row));
// mode 3: bias pair sum -> f32 dst: dst[i]=(a[ydecode(i)]+b[ydecode(i)])*scale(i)
struct Cvt { const void* src; const void* src2; bf16* dst; int n; int mode; };
struct CvtAll { Cvt t[17]; };

__global__ void convert_inputs(CvtAll ca, int* __restrict__ flag) {
    __shared__ int sflag;
    {
        const unsigned short* xb = (const unsigned short*)ca.t[0].src;
        int cnt = 0;
        for (int i = threadIdx.x; i < 1024; i += blockDim.x) {
            int e = (xb[i] >> 7) & 0xFF;
            cnt += (e >= 0xC8);
        }
        if (threadIdx.x == 0) sflag = 0;
        __syncthreads();
        if (cnt) atomicAdd(&sflag, cnt);
        __syncthreads();
    }
    const bool isf32 = (sflag >= 16);
    if (blockIdx.x == 0 && threadIdx.x == 0) *flag = isf32 ? 1 : 0;

    const int stride = gridDim.x * blockDim.x;
    const int tid0 = blockIdx.x * blockDim.x + threadIdx.x;
#pragma unroll 1
    for (int k = 0; k < 17; k++) {
        const int n = ca.t[k].n, mode = ca.t[k].mode;
        if (mode == 3) {
            const float* a32 = (const float*)ca.t[k].src;
            const float* b32 = (const float*)ca.t[k].src2;
            const short* a16 = (const short*)ca.t[k].src;
            const short* b16 = (const short*)ca.t[k].src2;
            float* df = (float*)ca.t[k].dst;
            for (int i = tid0; i < n; i += stride) {
                int yd = ydecode(i);
                float va = isf32 ? a32[yd] : bfs2f(a16[yd]);
                float vb = isf32 ? b32[yd] : bfs2f(b16[yd]);
                float m = ((((unsigned)i >> 2) & 3) == 2) ? TWOL : LOG2E;
                df[i] = (va + vb) * m;
            }
            continue;
        }
        const int n8 = n >> 3;
        bf16* d = ca.t[k].dst;
        for (int i = tid0; i < n8; i += stride) {
            int si = i;
            float m = 1.f;
            bool scaled = false;
            if (mode == 1) {
                m = ((((unsigned)i >> 11) & 3) == 2) ? TWOL : LOG2E; scaled = true;
            } else if (mode == 2) {
                int row = i >> 4;
                si = ydecode(row) * 16 + (i & 15);
                m = ((((unsigned)row >> 2) & 3) == 2) ? TWOL : LOG2E; scaled = true;
            }
            short8 ov;
            if (isf32) {
                const float4v* sp = (const float4v*)ca.t[k].src;
                float4v a = sp[2 * si], b = sp[2 * si + 1];
#pragma unroll
                for (int j = 0; j < 4; j++) {
                    ov[j]     = f2bfs(a[j] * m);
                    ov[4 + j] = f2bfs(b[j] * m);
                }
            } else {
                short8 sv = ((const short8*)ca.t[k].src)[si];
                if (scaled) {
#pragma unroll
                    for (int j = 0; j < 8; j++) ov[j] = f2bfs(bfs2f(sv[j]) * m);
                } else ov = sv;
            }
            ((short8*)d)[i] = ov;
        }
        // defensive scalar tail (all our sizes are multiples of 8)
        if (mode == 0)
            for (int i = (n8 << 3) + tid0; i < n; i += stride) {
                float v = isf32 ? ((const float*)ca.t[k].src)[i]
                                : bfs2f(((const short*)ca.t[k].src)[i]);
                d[i] = f2bf(v);
            }
    }
}

// ---------------------------------------------------------------------------
// Fused layer entry: Y = (relu(X@Wp^T+bp)) @ Wihp^T(+bsum), permuted layout via
// PRE-PERMUTED weights: row pos = cc*128 + lid*8 + ct is linear. short8 stores.
// ---------------------------------------------------------------------------
__global__ __launch_bounds__(256, 2) void fused_xp_y(
    const bf16* __restrict__ X, const bf16* __restrict__ Wp, const bf16* __restrict__ bp,
    const bf16* __restrict__ Wihp, const float* __restrict__ bsum,
    bf16* __restrict__ Yout, int N)
{
    __shared__ bf16 T[64][136];
    const int tid = threadIdx.x;
    const int w = tid >> 6, l = tid & 63, q = l >> 4, lid = l & 15;
    const int rowbase = blockIdx.x * 64;

    int arow = rowbase + w * 16 + lid;
    if (arow >= N) arow = N - 1;

    floatx4 acc[8];
    short8 bfrag[8][4];
    float bvv[8];

    // ---- stage A: xp = relu(X@Wp^T + bp) -> T (cols lid*8+ct) ----
#pragma unroll
    for (int ct = 0; ct < 8; ct++) acc[ct] = (floatx4)(0.f);
#pragma unroll
    for (int ct = 0; ct < 8; ct++) {
        int j = lid * 8 + ct;
        bvv[ct] = bf2f(bp[j]);
#pragma unroll
        for (int kt = 0; kt < 4; kt++)
            bfrag[ct][kt] = *(const short8*)(Wp + (size_t)j * 128 + kt * 32 + q * 8);
    }
#pragma unroll
    for (int kt = 0; kt < 4; kt++) {
        short8 af = *(const short8*)(X + (size_t)arow * 128 + kt * 32 + q * 8);
#pragma unroll
        for (int ct = 0; ct < 8; ct++)
            acc[ct] = __builtin_amdgcn_mfma_f32_16x16x32_bf16(af, bfrag[ct][kt], acc[ct], 0, 0, 0);
    }
#pragma unroll
    for (int r = 0; r < 4; r++) {
        short8 ov;
#pragma unroll
        for (int ct = 0; ct < 8; ct++)
            ov[ct] = f2bfs(fmaxf(acc[ct][r] + bvv[ct], 0.f));
        *(short8*)&T[w * 16 + q * 4 + r][lid * 8] = ov;
    }
    __syncthreads();

    // ---- stage B: Y chunks; linear permuted-weight rows; short8 stores ----
#pragma unroll 1
    for (int cc = 0; cc < 4; cc++) {
#pragma unroll
        for (int ct = 0; ct < 8; ct++) {
            int pos = cc * 128 + lid * 8 + ct;
            bvv[ct] = bsum[pos];
#pragma unroll
            for (int kt = 0; kt < 4; kt++)
                bfrag[ct][kt] = *(const short8*)(Wihp + (size_t)pos * 128 + kt * 32 + q * 8);
        }
#pragma unroll
        for (int ct = 0; ct < 8; ct++) acc[ct] = (floatx4)(0.f);
#pragma unroll
        for (int kt = 0; kt < 4; kt++) {
            short8 af = *(const short8*)&T[w * 16 + lid][kt * 32 + q * 8];
#pragma unroll
            for (int ct = 0; ct < 8; ct++)
                acc[ct] = __builtin_amdgcn_mfma_f32_16x16x32_bf16(af, bfrag[ct][kt], acc[ct], 0, 0, 0);
        }
#pragma unroll
        for (int r = 0; r < 4; r++) {
            int row = rowbase + w * 16 + q * 4 + r;
            if (row < N) {
                short8 ov;
#pragma unroll
                for (int ct = 0; ct < 8; ct++)
                    ov[ct] = f2bfs(acc[ct][r] + bvv[ct]);
                *(short8*)(Yout + (size_t)row * 512 + cc * 128 + lid * 8) = ov;
            }
        }
    }
}

// ---------------------------------------------------------------------------
// Fused between-layers: h1 = relu(aggr@Wl^T+bl+X@Wr^T); xp2 = relu(h1@Wp2^T+bp2);
// Y2 via pre-permuted Wihp2/bsum2. lid*8+ct lane remap; vector stores.
// ---------------------------------------------------------------------------
__global__ __launch_bounds__(256, 2) void fused_lin_xp_y(
    const bf16* __restrict__ aggr, const bf16* __restrict__ Wl, const bf16* __restrict__ bl,
    const bf16* __restrict__ X, const bf16* __restrict__ Wr,
    bf16* __restrict__ h1out,
    const bf16* __restrict__ Wp2, const bf16* __restrict__ bp2,
    const bf16* __restrict__ Wihp2, const float* __restrict__ bsum2,
    bf16* __restrict__ Yout, int N)
{
    __shared__ bf16 T1[64][136];
    __shared__ bf16 T2[64][136];
    const int tid = threadIdx.x;
    const int w = tid >> 6, l = tid & 63, q = l >> 4, lid = l & 15;
    const int rowbase = blockIdx.x * 64;

    int arow = rowbase + w * 16 + lid;
    if (arow >= N) arow = N - 1;

    floatx4 acc[8];
    short8 bfrag[8][4];
    float bvv[8];

    // ---- stage A: h1 ----
#pragma unroll
    for (int ct = 0; ct < 8; ct++) acc[ct] = (floatx4)(0.f);
#pragma unroll
    for (int ct = 0; ct < 8; ct++) {
        int j = lid * 8 + ct;
        bvv[ct] = bf2f(bl[j]);
#pragma unroll
        for (int kt = 0; kt < 4; kt++)
            bfrag[ct][kt] = *(const short8*)(Wl + (size_t)j * 128 + kt * 32 + q * 8);
    }
#pragma unroll
    for (int kt = 0; kt < 4; kt++) {
        short8 af = *(const short8*)(aggr + (size_t)arow * 128 + kt * 32 + q * 8);
#pragma unroll
        for (int ct = 0; ct < 8; ct++)
            acc[ct] = __builtin_amdgcn_mfma_f32_16x16x32_bf16(af, bfrag[ct][kt], acc[ct], 0, 0, 0);
    }
#pragma unroll
    for (int ct = 0; ct < 8; ct++) {
        int j = lid * 8 + ct;
#pragma unroll
        for (int kt = 0; kt < 4; kt++)
            bfrag[ct][kt] = *(const short8*)(Wr + (size_t)j * 128 + kt * 32 + q * 8);
    }
#pragma unroll
    for (int kt = 0; kt < 4; kt++) {
        short8 af = *(const short8*)(X + (size_t)arow * 128 + kt * 32 + q * 8);
#pragma unroll
        for (int ct = 0; ct < 8; ct++)
            acc[ct] = __builtin_amdgcn_mfma_f32_16x16x32_bf16(af, bfrag[ct][kt], acc[ct], 0, 0, 0);
    }
#pragma unroll
    for (int r = 0; r < 4; r++) {
        short8 ov;
#pragma unroll
        for (int ct = 0; ct < 8; ct++)
            ov[ct] = f2bfs(fmaxf(acc[ct][r] + bvv[ct], 0.f));
        int rl = w * 16 + q * 4 + r;
        *(short8*)&T1[rl][lid * 8] = ov;
        int row = rowbase + rl;
        if (row < N) *(short8*)(h1out + (size_t)row * 128 + lid * 8) = ov;
    }
    __syncthreads();

    // ---- stage B: xp2 -> T2 ----
#pragma unroll
    for (int ct = 0; ct < 8; ct++) {
        int j = lid * 8 + ct;
        bvv[ct] = bf2f(bp2[j]);
#pragma unroll
        for (int kt = 0; kt < 4; kt++)
            bfrag[ct][kt] = *(const short8*)(Wp2 + (size_t)j * 128 + kt * 32 + q * 8);
    }
#pragma unroll
    for (int ct = 0; ct < 8; ct++) acc[ct] = (floatx4)(0.f);
#pragma unroll
    for (int kt = 0; kt < 4; kt++) {
        short8 af = *(const short8*)&T1[w * 16 + lid][kt * 32 + q * 8];
#pragma unroll
        for (int ct = 0; ct < 8; ct++)
            acc[ct] = __builtin_amdgcn_mfma_f32_16x16x32_bf16(af, bfrag[ct][kt], acc[ct], 0, 0, 0);
    }
#pragma unroll
    for (int r = 0; r < 4; r++) {
        short8 ov;
#pragma unroll
        for (int ct = 0; ct < 8; ct++)
            ov[ct] = f2bfs(fmaxf(acc[ct][r] + bvv[ct], 0.f));
        *(short8*)&T2[w * 16 + q * 4 + r][lid * 8] = ov;
    }
    __syncthreads();

    // ---- stage C: Y2 chunks (linear permuted-weight rows) ----
#pragma unroll 1
    for (int cc = 0; cc < 4; cc++) {
#pragma unroll
        for (int ct = 0; ct < 8; ct++) {
            int pos = cc * 128 + lid * 8 + ct;
            bvv[ct] = bsum2[pos];
#pragma unroll
            for (int kt = 0; kt < 4; kt++)
                bfrag[ct][kt] = *(const short8*)(Wihp2 + (size_t)pos * 128 + kt * 32 + q * 8);
        }
#pragma unroll
        for (int ct = 0; ct < 8; ct++) acc[ct] = (floatx4)(0.f);
#pragma unroll
        for (int kt = 0; kt < 4; kt++) {
            short8 af = *(const short8*)&T2[w * 16 + lid][kt * 32 + q * 8];
#pragma unroll
            for (int ct = 0; ct < 8; ct++)
                acc[ct] = __builtin_amdgcn_mfma_f32_16x16x32_bf16(af, bfrag[ct][kt], acc[ct], 0, 0, 0);
        }
#pragma unroll
        for (int r = 0; r < 4; r++) {
            int row = rowbase + w * 16 + q * 4 + r;
            if (row < N) {
                short8 ov;
#pragma unroll
                for (int ct = 0; ct < 8; ct++)
                    ov[ct] = f2bfs(acc[ct][r] + bvv[ct]);
                *(short8*)(Yout + (size_t)row * 512 + cc * 128 + lid * 8) = ov;
            }
        }
    }
}

// ---------------------------------------------------------------------------
// LSTM neighbor aggregation (r14/r17 plateau core, 194.6us measured).
// template<EPI>: EPI=0 -> final h written to aggr (layer 1).
//                EPI=1 -> final h kept in hb LDS; epilogue computes
//                         out = h@Wl2^T + bl2 + h1@Wr2^T for the block's own
//                         16 nodes (waves 0-2), flag-aware f32/bf16 store.
// ---------------------------------------------------------------------------
template <int EPI>
__global__ __launch_bounds__(512, 4) void lstm_aggr(
    const bf16* __restrict__ Y,     // [N,512] PERMUTED, prescaled pre-activations
    const int* __restrict__ esrc,   // [N,16]
    const bf16* __restrict__ Whh,   // [512,128] prescaled by gate
    bf16* __restrict__ aggr,        // [N,128] out: final h (EPI=0)
    int N,
    const bf16* __restrict__ Wl2, const bf16* __restrict__ bl2,
    const bf16* __restrict__ Wr2, const bf16* __restrict__ h1,
    void* __restrict__ outp, const int* __restrict__ oflag)
{
    __shared__ alignas(16) short stage[2][8][1024];  // [buf][wave][2KB slice]
    __shared__ alignas(16) bf16 hb[2][16][136];
    __shared__ int srcl[16][16];    // [t][node]

    const int tid = threadIdx.x;
    const int w = tid >> 6, l = tid & 63, q = l >> 4, lid = l & 15;
    const int nodebase = blockIdx.x * 16;   // N = 50000 = 3125*16, exact

    if (tid < 256) {
        int node = tid >> 4, t = tid & 15;
        srcl[t][node] = esrc[(size_t)(nodebase + node) * 16 + t];
    }

    // Whh A-fragments: wf[g][kt]; A-row = gatecol = g*128 + 16*w + lid
    short8 wf[4][4];
#pragma unroll
    for (int g = 0; g < 4; g++) {
        int gc = g * 128 + 16 * w + lid;
#pragma unroll
        for (int kt = 0; kt < 4; kt++)
            wf[g][kt] = *(const short8*)(Whh + (size_t)gc * 128 + kt * 32 + q * 8);
    }

    float c[4];
#pragma unroll
    for (int r = 0; r < 4; r++) c[r] = 0.f;

    const int laneoff = w * 64 + q * 8;

    __syncthreads();   // srcl visible before first DMA

    // prologue: pairs 0,1 -> bufs 0,1 (oldest-first)
    {
        int s0 = srcl[0][lid];
        dma2(Y + (size_t)s0 * 512 + laneoff, &stage[0][w][0], &stage[0][w][512]);
        int s1 = srcl[1][lid];
        dma2(Y + (size_t)s1 * 512 + laneoff, &stage[1][w][0], &stage[1][w][512]);
    }

#pragma unroll 2
    for (int t = 0; t < 16; t++) {
        const int cb = t & 1;

        if (t == 15) asm volatile("s_waitcnt vmcnt(0)" ::: "memory");
        else         asm volatile("s_waitcnt vmcnt(2)" ::: "memory");

        int snext = (t < 14) ? srcl[t + 2][lid] : 0;

        floatx4 acc[4];
        {
            const short* wbuf = &stage[cb][w][0];
            short8 y0 = *(const short8*)&wbuf[q * 256 + lid * 8];
            short8 y1 = *(const short8*)&wbuf[q * 256 + 128 + lid * 8];
#pragma unroll
            for (int g = 0; g < 2; g++)
#pragma unroll
                for (int r = 0; r < 4; r++) {
                    acc[g][r]     = bfs2f(y0[g * 4 + r]);
                    acc[2 + g][r] = bfs2f(y1[g * 4 + r]);
                }
        }

        if (t) {   // h0 = 0: skip recurrent MFMA at t=0
#pragma unroll
            for (int kt = 0; kt < 4; kt++) {
                short8 bh = *(const short8*)&hb[cb][lid][kt * 32 + q * 8];
#pragma unroll
                for (int g = 0; g < 4; g++)
                    acc[g] = __builtin_amdgcn_mfma_f32_16x16x32_bf16(wf[g][kt], bh, acc[g], 0, 0, 0);
            }
        }

        {
            short4v hv;
#pragma unroll
            for (int r = 0; r < 4; r++)
                hv[r] = f2bfs(cell(acc[0][r], acc[1][r], acc[2][r], acc[3][r], c[r]));
            if (t < 15) *(short4v*)&hb[cb ^ 1][lid][16 * w + 4 * q] = hv;
            else if (EPI == 0)
                *(short4v*)(aggr + (size_t)(nodebase + lid) * 128 + 16 * w + 4 * q) = hv;
            else
                *(short4v*)&hb[0][lid][16 * w + 4 * q] = hv;   // cb^1 at t=15
        }

        if (t < 15) {
            asm volatile("s_waitcnt lgkmcnt(0)" ::: "memory");
            if (t < 14)
                dma2(Y + (size_t)snext * 512 + laneoff, &stage[cb][w][0], &stage[cb][w][512]);
            __builtin_amdgcn_s_barrier();   // hb exchange only — no vmcnt drain
        }
    }

    if constexpr (EPI == 1) {
        // out = h@Wl2^T + bl2 + h1@Wr2^T for nodes [nodebase, nodebase+16)
        asm volatile("s_waitcnt lgkmcnt(0)" ::: "memory");
        __builtin_amdgcn_s_barrier();      // hb[0] complete
        if (w < 3) {                       // 3 col-tiles cover C=40
            int j = w * 16 + lid;
            int jc = j < 40 ? j : 39;
            short8 blf[4], brf[4];
#pragma unroll
            for (int kt = 0; kt < 4; kt++) {
                blf[kt] = *(const short8*)(Wl2 + (size_t)jc * 128 + kt * 32 + q * 8);
                brf[kt] = *(const short8*)(Wr2 + (size_t)jc * 128 + kt * 32 + q * 8);
            }
            floatx4 o = (floatx4)(0.f);
#pragma unroll
            for (int kt = 0; kt < 4; kt++) {
                short8 ah = *(const short8*)&hb[0][lid][kt * 32 + q * 8];
                o = __builtin_amdgcn_mfma_f32_16x16x32_bf16(ah, blf[kt], o, 0, 0, 0);
            }
#pragma unroll
            for (int kt = 0; kt < 4; kt++) {
                short8 a1 = *(const short8*)(h1 + (size_t)(nodebase + lid) * 128 + kt * 32 + q * 8);
                o = __builtin_amdgcn_mfma_f32_16x16x32_bf16(a1, brf[kt], o, 0, 0, 0);
            }
            float bv = bf2f(bl2[jc]);
            bool of32 = (*oflag != 0);
            if (j < 40) {
#pragma unroll
                for (int r = 0; r < 4; r++) {
                    int node = nodebase + q * 4 + r;
                    float v = o[r] + bv;
                    size_t idx = (size_t)node * 40 + j;
                    if (of32) ((float*)outp)[idx] = v;
                    else      ((bf16*)outp)[idx]  = f2bf(v);
                }
            }
        }
    }
}

extern "C" void kernel_launch(void* const* d_in, const int* in_sizes, int n_in,
                              void* d_out, int out_size, void* d_ws, size_t ws_size,
                              hipStream_t stream)
{
    const int N = 50000;
    const int* es = (const int*)d_in[1];
    char* ws = (char*)d_ws;

    // d_in: x=0; L1: Wp=8,bp=9,Wih=10,Whh=11,bih=12,bhh=13,Wl=14,bl=15,Wr=16; L2: +9
    // conv entries: idx into d_in, mode, (second src for mode 3)
    struct Ent { int di; int di2; int mode; int n; };
    Ent ents[17] = {
        {0,  -1, 0, 0},                      // x
        {8,  -1, 0, 0}, {9,  -1, 0, 0},      // Wp1, bp1
        {10, -1, 2, 0}, {11, -1, 1, 0},      // Wihp1, Whh1
        {12, 13, 3, 0},                      // bsum1 (f32)
        {14, -1, 0, 0}, {15, -1, 0, 0}, {16, -1, 0, 0},  // Wl1, bl1, Wr1
        {17, -1, 0, 0}, {18, -1, 0, 0},      // Wp2, bp2
        {19, -1, 2, 0}, {20, -1, 1, 0},      // Wihp2, Whh2
        {21, 22, 3, 0},                      // bsum2 (f32)
        {23, -1, 0, 0}, {24, -1, 0, 0}, {25, -1, 0, 0},  // Wl2, bl2, Wr2
    };
    bf16* conv[17];
    size_t off = 0;
    CvtAll ca;
    for (int k = 0; k < 17; k++) {
        conv[k] = (bf16*)ws + off;
        int n = in_sizes[ents[k].di];
        ca.t[k].src  = d_in[ents[k].di];
        ca.t[k].src2 = ents[k].di2 >= 0 ? d_in[ents[k].di2] : nullptr;
        ca.t[k].dst  = conv[k];
        ca.t[k].n    = n;
        ca.t[k].mode = ents[k].mode;
        size_t elems = (ents[k].mode == 3) ? (size_t)n * 2 : (size_t)n;  // f32 dst
        off += (elems + 63) & ~(size_t)63;
    }
    int* flag  = (int*)(ws + ((size_t)15 << 20));
    bf16* aggr = (bf16*)(ws + ((size_t)16 << 20));   // [N,128] (layer-1 only)
    bf16* Y    = (bf16*)(ws + ((size_t)30 << 20));   // [N,512] permuted
    bf16* h1   = (bf16*)(ws + ((size_t)84 << 20));   // [N,128]

    const bf16 *xc   = conv[0];
    const bf16 *Wp1  = conv[1],  *bp1 = conv[2];
    const bf16 *Wihp1 = conv[3], *Whh1 = conv[4];
    const float *bsum1 = (const float*)conv[5];
    const bf16 *Wl1 = conv[6], *bl1 = conv[7], *Wr1 = conv[8];
    const bf16 *Wp2 = conv[9], *bp2 = conv[10];
    const bf16 *Wihp2 = conv[11], *Whh2 = conv[12];
    const float *bsum2 = (const float*)conv[13];
    const bf16 *Wl2 = conv[14], *bl2 = conv[15], *Wr2 = conv[16];

    dim3 blk(256);
    const int gx = (N + 63) / 64;    // 782
    const int gl = N / 16;           // 3125 (exact)

    convert_inputs<<<dim3(1024), blk, 0, stream>>>(ca, flag);

    // ---- layer 1 ----
    fused_xp_y<<<dim3(gx), blk, 0, stream>>>(xc, Wp1, bp1, Wihp1, bsum1, Y, N);
    lstm_aggr<0><<<dim3(gl), dim3(512), 0, stream>>>(
        Y, es, Whh1, aggr, N, nullptr, nullptr, nullptr, nullptr, nullptr, nullptr);

    // ---- between layers: lin1 -> xp2 -> Y2 ----
    fused_lin_xp_y<<<dim3(gx), blk, 0, stream>>>(
        aggr, Wl1, bl1, xc, Wr1, h1, Wp2, bp2, Wihp2, bsum2, Y, N);

    // ---- layer 2 + fused final linear ----
    lstm_aggr<1><<<dim3(gl), dim3(512), 0, stream>>>(
        Y, es, Whh2, aggr, N, Wl2, bl2, Wr2, h1, d_out, flag);
}

// Round 6
// 575.350 us; speedup vs baseline: 1.2155x; 1.1394x over previous
//
#include <hip/hip_runtime.h>
#include <hip/hip_bf16.h>

// GCN_5016521802361: 2x SAGEConv(aggr='lstm', project=True), N=50000, D=16, F=128, C=40.
// Round 19:
//  - lstm2 (EPI=1) epilogue latency hiding: at t=15 the dead stage[0] buffer
//    receives the block's 16 h1 rows via global_load_lds (issued after the t=15
//    vmcnt(0); flies under t=15 MFMA+cell). Wl2/Wr2 issued before the final
//    barrier. Epilogue reads h1 from LDS. No extra loop-live registers.
//  - Producers stage B/C: wave-per-chunk restructure. Wave w owns col chunk
//    cc=w; weight fragments loaded ONCE (32 loads/thread, was 128) and reused
//    across the 4 row-tiles of T (LDS). 4x less L2 weight traffic. Accumulation
//    order unchanged -> bit-identical Y.
//  - Everything else r18 (pre-permuted Wihp, f32 bsum, fused final linear).

typedef __hip_bfloat16 bf16;
typedef __attribute__((ext_vector_type(8))) short short8;
typedef __attribute__((ext_vector_type(4))) short short4v;
typedef __attribute__((ext_vector_type(4))) float floatx4;
typedef __attribute__((ext_vector_type(4))) float float4v;

#define LOG2E 1.4426950408889634f
#define TWOL  2.8853900817779268f

__device__ __forceinline__ float bf2f(bf16 v) { return __bfloat162float(v); }
__device__ __forceinline__ bf16  f2bf(float v) { return __float2bfloat16(v); }
__device__ __forceinline__ float bfs2f(short s) {
    union { float f; unsigned u; } v; v.u = ((unsigned)(unsigned short)s) << 16; return v.f;
}
__device__ __forceinline__ short f2bfs(float v) {
    bf16 b = __float2bfloat16(v); return *(short*)&b;
}

__device__ __forceinline__ float ex2(float x) {
#if __has_builtin(__builtin_amdgcn_exp2f)
    return __builtin_amdgcn_exp2f(x);
#else
    return exp2f(x);
#endif
}

// LSTM cell, prescaled inputs: i_,f_,o_ carry log2e, g_ carries 2*log2e,
// c is tracked as (2*log2e)*c_true. Single merged rcp on the c path.
__device__ __forceinline__ float cell(float i_, float f_, float g_, float o_, float& c) {
    float ei = ex2(-i_), ef = ex2(-f_), eg = ex2(g_), eo = ex2(-o_);
    float A = (1.f + ei) * (eg + 1.f);
    float B = 1.f + ef;
    float cn = fmaf(c, A, fmaf(eg, TWOL, -TWOL) * B) * __builtin_amdgcn_rcpf(A * B);
    c = cn;
    float ec = ex2(cn);
    return (ec - 1.f) * __builtin_amdgcn_rcpf((ec + 1.f) * (1.f + eo));
}

// Permuted-Y memory position p -> source gate row. Convert-time only.
__device__ __forceinline__ int ydecode(int p) {
    int pw = (p >> 6) & 7, pq = (p >> 4) & 3, pg = (p >> 2) & 3, pr = p & 3;
    return pg * 128 + pw * 16 + pq * 4 + pr;
}

__device__ __forceinline__ void dma1(const bf16* gp, void* lp) {
    __builtin_amdgcn_global_load_lds(
        (const __attribute__((address_space(1))) void*)gp,
        (__attribute__((address_space(3))) void*)lp, 16, 0, 0);
}

// two 16B/lane global->LDS DMAs covering a wave's 2KB slice
__device__ __forceinline__ void dma2(const bf16* gp, void* lp0, void* lp1) {
    dma1(gp, lp0);
    dma1(gp + 32, lp1);
}

// mode 0: plain copy; mode 1: Whh gate-scale (gate=(elem>>14)&3);
// mode 2: Wih permute+scale (dest row=elem>>7, src row=ydecode(row));
// mode 3: bias pair sum -> f32 dst: dst[i]=(a[ydecode(i)]+b[ydecode(i)])*scale(i)
struct Cvt { const void* src; const void* src2; bf16* dst; int n; int mode; };
struct CvtAll { Cvt t[17]; };

__global__ void convert_inputs(CvtAll ca, int* __restrict__ flag) {
    __shared__ int sflag;
    {
        const unsigned short* xb = (const unsigned short*)ca.t[0].src;
        int cnt = 0;
        for (int i = threadIdx.x; i < 1024; i += blockDim.x) {
            int e = (xb[i] >> 7) & 0xFF;
            cnt += (e >= 0xC8);
        }
        if (threadIdx.x == 0) sflag = 0;
        __syncthreads();
        if (cnt) atomicAdd(&sflag, cnt);
        __syncthreads();
    }
    const bool isf32 = (sflag >= 16);
    if (blockIdx.x == 0 && threadIdx.x == 0) *flag = isf32 ? 1 : 0;

    const int stride = gridDim.x * blockDim.x;
    const int tid0 = blockIdx.x * blockDim.x + threadIdx.x;
#pragma unroll 1
    for (int k = 0; k < 17; k++) {
        const int n = ca.t[k].n, mode = ca.t[k].mode;
        if (mode == 3) {
            const float* a32 = (const float*)ca.t[k].src;
            const float* b32 = (const float*)ca.t[k].src2;
            const short* a16 = (const short*)ca.t[k].src;
            const short* b16 = (const short*)ca.t[k].src2;
            float* df = (float*)ca.t[k].dst;
            for (int i = tid0; i < n; i += stride) {
                int yd = ydecode(i);
                float va = isf32 ? a32[yd] : bfs2f(a16[yd]);
                float vb = isf32 ? b32[yd] : bfs2f(b16[yd]);
                float m = ((((unsigned)i >> 2) & 3) == 2) ? TWOL : LOG2E;
                df[i] = (va + vb) * m;
            }
            continue;
        }
        const int n8 = n >> 3;
        bf16* d = ca.t[k].dst;
        for (int i = tid0; i < n8; i += stride) {
            int si = i;
            float m = 1.f;
            bool scaled = false;
            if (mode == 1) {
                m = ((((unsigned)i >> 11) & 3) == 2) ? TWOL : LOG2E; scaled = true;
            } else if (mode == 2) {
                int row = i >> 4;
                si = ydecode(row) * 16 + (i & 15);
                m = ((((unsigned)row >> 2) & 3) == 2) ? TWOL : LOG2E; scaled = true;
            }
            short8 ov;
            if (isf32) {
                const float4v* sp = (const float4v*)ca.t[k].src;
                float4v a = sp[2 * si], b = sp[2 * si + 1];
#pragma unroll
                for (int j = 0; j < 4; j++) {
                    ov[j]     = f2bfs(a[j] * m);
                    ov[4 + j] = f2bfs(b[j] * m);
                }
            } else {
                short8 sv = ((const short8*)ca.t[k].src)[si];
                if (scaled) {
#pragma unroll
                    for (int j = 0; j < 8; j++) ov[j] = f2bfs(bfs2f(sv[j]) * m);
                } else ov = sv;
            }
            ((short8*)d)[i] = ov;
        }
        if (mode == 0)
            for (int i = (n8 << 3) + tid0; i < n; i += stride) {
                float v = isf32 ? ((const float*)ca.t[k].src)[i]
                                : bfs2f(((const short*)ca.t[k].src)[i]);
                d[i] = f2bf(v);
            }
    }
}

// ---------------------------------------------------------------------------
// Fused layer entry: Y = (relu(X@Wp^T+bp)) @ Wihp^T(+bsum), permuted layout.
// Stage B: wave w owns col chunk w; weights loaded once, reused over 4 rowtiles.
// ---------------------------------------------------------------------------
__global__ __launch_bounds__(256, 2) void fused_xp_y(
    const bf16* __restrict__ X, const bf16* __restrict__ Wp, const bf16* __restrict__ bp,
    const bf16* __restrict__ Wihp, const float* __restrict__ bsum,
    bf16* __restrict__ Yout, int N)
{
    __shared__ bf16 T[64][136];
    const int tid = threadIdx.x;
    const int w = tid >> 6, l = tid & 63, q = l >> 4, lid = l & 15;
    const int rowbase = blockIdx.x * 64;

    int arow = rowbase + w * 16 + lid;
    if (arow >= N) arow = N - 1;

    floatx4 acc[8];
    short8 bfrag[8][4];
    float bvv[8];

    // ---- stage A: xp = relu(X@Wp^T + bp) -> T (cols lid*8+ct) ----
#pragma unroll
    for (int ct = 0; ct < 8; ct++) acc[ct] = (floatx4)(0.f);
#pragma unroll
    for (int ct = 0; ct < 8; ct++) {
        int j = lid * 8 + ct;
        bvv[ct] = bf2f(bp[j]);
#pragma unroll
        for (int kt = 0; kt < 4; kt++)
            bfrag[ct][kt] = *(const short8*)(Wp + (size_t)j * 128 + kt * 32 + q * 8);
    }
#pragma unroll
    for (int kt = 0; kt < 4; kt++) {
        short8 af = *(const short8*)(X + (size_t)arow * 128 + kt * 32 + q * 8);
#pragma unroll
        for (int ct = 0; ct < 8; ct++)
            acc[ct] = __builtin_amdgcn_mfma_f32_16x16x32_bf16(af, bfrag[ct][kt], acc[ct], 0, 0, 0);
    }
#pragma unroll
    for (int r = 0; r < 4; r++) {
        short8 ov;
#pragma unroll
        for (int ct = 0; ct < 8; ct++)
            ov[ct] = f2bfs(fmaxf(acc[ct][r] + bvv[ct], 0.f));
        *(short8*)&T[w * 16 + q * 4 + r][lid * 8] = ov;
    }
    __syncthreads();

    // ---- stage B: wave w = col chunk w; weights once, 4 rowtiles ----
#pragma unroll
    for (int ct = 0; ct < 8; ct++) {
        int pos = w * 128 + lid * 8 + ct;
        bvv[ct] = bsum[pos];
#pragma unroll
        for (int kt = 0; kt < 4; kt++)
            bfrag[ct][kt] = *(const short8*)(Wihp + (size_t)pos * 128 + kt * 32 + q * 8);
    }
#pragma unroll 1
    for (int rt = 0; rt < 4; rt++) {
#pragma unroll
        for (int ct = 0; ct < 8; ct++) acc[ct] = (floatx4)(0.f);
#pragma unroll
        for (int kt = 0; kt < 4; kt++) {
            short8 af = *(const short8*)&T[rt * 16 + lid][kt * 32 + q * 8];
#pragma unroll
            for (int ct = 0; ct < 8; ct++)
                acc[ct] = __builtin_amdgcn_mfma_f32_16x16x32_bf16(af, bfrag[ct][kt], acc[ct], 0, 0, 0);
        }
#pragma unroll
        for (int r = 0; r < 4; r++) {
            int row = rowbase + rt * 16 + q * 4 + r;
            if (row < N) {
                short8 ov;
#pragma unroll
                for (int ct = 0; ct < 8; ct++)
                    ov[ct] = f2bfs(acc[ct][r] + bvv[ct]);
                *(short8*)(Yout + (size_t)row * 512 + w * 128 + lid * 8) = ov;
            }
        }
    }
}

// ---------------------------------------------------------------------------
// Fused between-layers: h1 = relu(aggr@Wl^T+bl+X@Wr^T); xp2 = relu(h1@Wp2^T+bp2);
// Y2 via pre-permuted Wihp2/bsum2 (stage C wave-per-chunk).
// ---------------------------------------------------------------------------
__global__ __launch_bounds__(256, 2) void fused_lin_xp_y(
    const bf16* __restrict__ aggr, const bf16* __restrict__ Wl, const bf16* __restrict__ bl,
    const bf16* __restrict__ X, const bf16* __restrict__ Wr,
    bf16* __restrict__ h1out,
    const bf16* __restrict__ Wp2, const bf16* __restrict__ bp2,
    const bf16* __restrict__ Wihp2, const float* __restrict__ bsum2,
    bf16* __restrict__ Yout, int N)
{
    __shared__ bf16 T1[64][136];
    __shared__ bf16 T2[64][136];
    const int tid = threadIdx.x;
    const int w = tid >> 6, l = tid & 63, q = l >> 4, lid = l & 15;
    const int rowbase = blockIdx.x * 64;

    int arow = rowbase + w * 16 + lid;
    if (arow >= N) arow = N - 1;

    floatx4 acc[8];
    short8 bfrag[8][4];
    float bvv[8];

    // ---- stage A: h1 ----
#pragma unroll
    for (int ct = 0; ct < 8; ct++) acc[ct] = (floatx4)(0.f);
#pragma unroll
    for (int ct = 0; ct < 8; ct++) {
        int j = lid * 8 + ct;
        bvv[ct] = bf2f(bl[j]);
#pragma unroll
        for (int kt = 0; kt < 4; kt++)
            bfrag[ct][kt] = *(const short8*)(Wl + (size_t)j * 128 + kt * 32 + q * 8);
    }
#pragma unroll
    for (int kt = 0; kt < 4; kt++) {
        short8 af = *(const short8*)(aggr + (size_t)arow * 128 + kt * 32 + q * 8);
#pragma unroll
        for (int ct = 0; ct < 8; ct++)
            acc[ct] = __builtin_amdgcn_mfma_f32_16x16x32_bf16(af, bfrag[ct][kt], acc[ct], 0, 0, 0);
    }
#pragma unroll
    for (int ct = 0; ct < 8; ct++) {
        int j = lid * 8 + ct;
#pragma unroll
        for (int kt = 0; kt < 4; kt++)
            bfrag[ct][kt] = *(const short8*)(Wr + (size_t)j * 128 + kt * 32 + q * 8);
    }
#pragma unroll
    for (int kt = 0; kt < 4; kt++) {
        short8 af = *(const short8*)(X + (size_t)arow * 128 + kt * 32 + q * 8);
#pragma unroll
        for (int ct = 0; ct < 8; ct++)
            acc[ct] = __builtin_amdgcn_mfma_f32_16x16x32_bf16(af, bfrag[ct][kt], acc[ct], 0, 0, 0);
    }
#pragma unroll
    for (int r = 0; r < 4; r++) {
        short8 ov;
#pragma unroll
        for (int ct = 0; ct < 8; ct++)
            ov[ct] = f2bfs(fmaxf(acc[ct][r] + bvv[ct], 0.f));
        int rl = w * 16 + q * 4 + r;
        *(short8*)&T1[rl][lid * 8] = ov;
        int row = rowbase + rl;
        if (row < N) *(short8*)(h1out + (size_t)row * 128 + lid * 8) = ov;
    }
    __syncthreads();

    // ---- stage B: xp2 -> T2 ----
#pragma unroll
    for (int ct = 0; ct < 8; ct++) {
        int j = lid * 8 + ct;
        bvv[ct] = bf2f(bp2[j]);
#pragma unroll
        for (int kt = 0; kt < 4; kt++)
            bfrag[ct][kt] = *(const short8*)(Wp2 + (size_t)j * 128 + kt * 32 + q * 8);
    }
#pragma unroll
    for (int ct = 0; ct < 8; ct++) acc[ct] = (floatx4)(0.f);
#pragma unroll
    for (int kt = 0; kt < 4; kt++) {
        short8 af = *(const short8*)&T1[w * 16 + lid][kt * 32 + q * 8];
#pragma unroll
        for (int ct = 0; ct < 8; ct++)
            acc[ct] = __builtin_amdgcn_mfma_f32_16x16x32_bf16(af, bfrag[ct][kt], acc[ct], 0, 0, 0);
    }
#pragma unroll
    for (int r = 0; r < 4; r++) {
        short8 ov;
#pragma unroll
        for (int ct = 0; ct < 8; ct++)
            ov[ct] = f2bfs(fmaxf(acc[ct][r] + bvv[ct], 0.f));
        *(short8*)&T2[w * 16 + q * 4 + r][lid * 8] = ov;
    }
    __syncthreads();

    // ---- stage C: wave w = col chunk w; weights once, 4 rowtiles ----
#pragma unroll
    for (int ct = 0; ct < 8; ct++) {
        int pos = w * 128 + lid * 8 + ct;
        bvv[ct] = bsum2[pos];
#pragma unroll
        for (int kt = 0; kt < 4; kt++)
            bfrag[ct][kt] = *(const short8*)(Wihp2 + (size_t)pos * 128 + kt * 32 + q * 8);
    }
#pragma unroll 1
    for (int rt = 0; rt < 4; rt++) {
#pragma unroll
        for (int ct = 0; ct < 8; ct++) acc[ct] = (floatx4)(0.f);
#pragma unroll
        for (int kt = 0; kt < 4; kt++) {
            short8 af = *(const short8*)&T2[rt * 16 + lid][kt * 32 + q * 8];
#pragma unroll
            for (int ct = 0; ct < 8; ct++)
                acc[ct] = __builtin_amdgcn_mfma_f32_16x16x32_bf16(af, bfrag[ct][kt], acc[ct], 0, 0, 0);
        }
#pragma unroll
        for (int r = 0; r < 4; r++) {
            int row = rowbase + rt * 16 + q * 4 + r;
            if (row < N) {
                short8 ov;
#pragma unroll
                for (int ct = 0; ct < 8; ct++)
                    ov[ct] = f2bfs(acc[ct][r] + bvv[ct]);
                *(short8*)(Yout + (size_t)row * 512 + w * 128 + lid * 8) = ov;
            }
        }
    }
}

// ---------------------------------------------------------------------------
// LSTM neighbor aggregation (r14/r17 plateau core).
// EPI=0: final h -> aggr. EPI=1: h stays in hb; h1 rows DMA'd into the dead
// stage[0] during t=15; epilogue (waves 0-2) computes out = h@Wl2^T+bl2+h1@Wr2^T.
// ---------------------------------------------------------------------------
template <int EPI>
__global__ __launch_bounds__(512, 4) void lstm_aggr(
    const bf16* __restrict__ Y,     // [N,512] PERMUTED, prescaled pre-activations
    const int* __restrict__ esrc,   // [N,16]
    const bf16* __restrict__ Whh,   // [512,128] prescaled by gate
    bf16* __restrict__ aggr,        // [N,128] out: final h (EPI=0)
    int N,
    const bf16* __restrict__ Wl2, const bf16* __restrict__ bl2,
    const bf16* __restrict__ Wr2, const bf16* __restrict__ h1,
    void* __restrict__ outp, const int* __restrict__ oflag)
{
    __shared__ alignas(16) short stage[2][8][1024];  // [buf][wave][2KB slice]
    __shared__ alignas(16) bf16 hb[2][16][136];
    __shared__ int srcl[16][16];    // [t][node]

    const int tid = threadIdx.x;
    const int w = tid >> 6, l = tid & 63, q = l >> 4, lid = l & 15;
    const int nodebase = blockIdx.x * 16;   // N = 50000 = 3125*16, exact

    if (tid < 256) {
        int node = tid >> 4, t = tid & 15;
        srcl[t][node] = esrc[(size_t)(nodebase + node) * 16 + t];
    }

    // Whh A-fragments: wf[g][kt]; A-row = gatecol = g*128 + 16*w + lid
    short8 wf[4][4];
#pragma unroll
    for (int g = 0; g < 4; g++) {
        int gc = g * 128 + 16 * w + lid;
#pragma unroll
        for (int kt = 0; kt < 4; kt++)
            wf[g][kt] = *(const short8*)(Whh + (size_t)gc * 128 + kt * 32 + q * 8);
    }

    float c[4];
#pragma unroll
    for (int r = 0; r < 4; r++) c[r] = 0.f;

    const int laneoff = w * 64 + q * 8;

    __syncthreads();   // srcl visible before first DMA

    // prologue: pairs 0,1 -> bufs 0,1 (oldest-first)
    {
        int s0 = srcl[0][lid];
        dma2(Y + (size_t)s0 * 512 + laneoff, &stage[0][w][0], &stage[0][w][512]);
        int s1 = srcl[1][lid];
        dma2(Y + (size_t)s1 * 512 + laneoff, &stage[1][w][0], &stage[1][w][512]);
    }

#pragma unroll 2
    for (int t = 0; t < 16; t++) {
        const int cb = t & 1;

        if (t == 15) asm volatile("s_waitcnt vmcnt(0)" ::: "memory");
        else         asm volatile("s_waitcnt vmcnt(2)" ::: "memory");

        // EPI=1: stage[0] is dead at t=15 (pair-14 retired) -> DMA the block's
        // 16 h1 rows (4KB) into it; flies under t=15's MFMA+cell.
        if (EPI == 1 && t == 15 && w < 4) {
            const bf16* gp = h1 + (size_t)(nodebase + w * 4 + q) * 128 + lid * 8;
            dma1(gp, (char*)&stage[0][0][0] + (tid << 4 & ~1023 ? 0 : 0) + w * 1024);
        }

        int snext = (t < 14) ? srcl[t + 2][lid] : 0;

        floatx4 acc[4];
        {
            const short* wbuf = &stage[cb][w][0];
            short8 y0 = *(const short8*)&wbuf[q * 256 + lid * 8];
            short8 y1 = *(const short8*)&wbuf[q * 256 + 128 + lid * 8];
#pragma unroll
            for (int g = 0; g < 2; g++)
#pragma unroll
                for (int r = 0; r < 4; r++) {
                    acc[g][r]     = bfs2f(y0[g * 4 + r]);
                    acc[2 + g][r] = bfs2f(y1[g * 4 + r]);
                }
        }

        if (t) {   // h0 = 0: skip recurrent MFMA at t=0
#pragma unroll
            for (int kt = 0; kt < 4; kt++) {
                short8 bh = *(const short8*)&hb[cb][lid][kt * 32 + q * 8];
#pragma unroll
                for (int g = 0; g < 4; g++)
                    acc[g] = __builtin_amdgcn_mfma_f32_16x16x32_bf16(wf[g][kt], bh, acc[g], 0, 0, 0);
            }
        }

        {
            short4v hv;
#pragma unroll
            for (int r = 0; r < 4; r++)
                hv[r] = f2bfs(cell(acc[0][r], acc[1][r], acc[2][r], acc[3][r], c[r]));
            if (t < 15) *(short4v*)&hb[cb ^ 1][lid][16 * w + 4 * q] = hv;
            else if (EPI == 0)
                *(short4v*)(aggr + (size_t)(nodebase + lid) * 128 + 16 * w + 4 * q) = hv;
            else
                *(short4v*)&hb[0][lid][16 * w + 4 * q] = hv;   // cb^1 at t=15
        }

        if (t < 15) {
            asm volatile("s_waitcnt lgkmcnt(0)" ::: "memory");
            if (t < 14)
                dma2(Y + (size_t)snext * 512 + laneoff, &stage[cb][w][0], &stage[cb][w][512]);
            __builtin_amdgcn_s_barrier();   // hb exchange only — no vmcnt drain
        }
    }

    if constexpr (EPI == 1) {
        // h1 DMA landed (issuer waves drain), Wl2/Wr2 issued pre-barrier.
        asm volatile("s_waitcnt vmcnt(0)" ::: "memory");
        short8 blf[4], brf[4];
        int j = w * 16 + lid;
        int jc = j < 40 ? j : 39;
        if (w < 3) {
#pragma unroll
            for (int kt = 0; kt < 4; kt++) {
                blf[kt] = *(const short8*)(Wl2 + (size_t)jc * 128 + kt * 32 + q * 8);
                brf[kt] = *(const short8*)(Wr2 + (size_t)jc * 128 + kt * 32 + q * 8);
            }
        }
        asm volatile("s_waitcnt lgkmcnt(0)" ::: "memory");
        __builtin_amdgcn_s_barrier();      // hb[0] + h1b complete
        if (w < 3) {                       // 3 col-tiles cover C=40
            const short* h1b = &stage[0][0][0];
            floatx4 o = (floatx4)(0.f);
#pragma unroll
            for (int kt = 0; kt < 4; kt++) {
                short8 ah = *(const short8*)&hb[0][lid][kt * 32 + q * 8];
                o = __builtin_amdgcn_mfma_f32_16x16x32_bf16(ah, blf[kt], o, 0, 0, 0);
            }
#pragma unroll
            for (int kt = 0; kt < 4; kt++) {
                short8 a1 = *(const short8*)&h1b[lid * 128 + kt * 32 + q * 8];
                o = __builtin_amdgcn_mfma_f32_16x16x32_bf16(a1, brf[kt], o, 0, 0, 0);
            }
            float bv = bf2f(bl2[jc]);
            bool of32 = (*oflag != 0);
            if (j < 40) {
#pragma unroll
                for (int r = 0; r < 4; r++) {
                    int node = nodebase + q * 4 + r;
                    float v = o[r] + bv;
                    size_t idx = (size_t)node * 40 + j;
                    if (of32) ((float*)outp)[idx] = v;
                    else      ((bf16*)outp)[idx]  = f2bf(v);
                }
            }
        }
    }
}

extern "C" void kernel_launch(void* const* d_in, const int* in_sizes, int n_in,
                              void* d_out, int out_size, void* d_ws, size_t ws_size,
                              hipStream_t stream)
{
    const int N = 50000;
    const int* es = (const int*)d_in[1];
    char* ws = (char*)d_ws;

    struct Ent { int di; int di2; int mode; };
    Ent ents[17] = {
        {0,  -1, 0},
        {8,  -1, 0}, {9,  -1, 0},            // Wp1, bp1
        {10, -1, 2}, {11, -1, 1},            // Wihp1, Whh1
        {12, 13, 3},                         // bsum1 (f32)
        {14, -1, 0}, {15, -1, 0}, {16, -1, 0},  // Wl1, bl1, Wr1
        {17, -1, 0}, {18, -1, 0},            // Wp2, bp2
        {19, -1, 2}, {20, -1, 1},            // Wihp2, Whh2
        {21, 22, 3},                         // bsum2 (f32)
        {23, -1, 0}, {24, -1, 0}, {25, -1, 0},  // Wl2, bl2, Wr2
    };
    bf16* conv[17];
    size_t off = 0;
    CvtAll ca;
    for (int k = 0; k < 17; k++) {
        conv[k] = (bf16*)ws + off;
        int n = in_sizes[ents[k].di];
        ca.t[k].src  = d_in[ents[k].di];
        ca.t[k].src2 = ents[k].di2 >= 0 ? d_in[ents[k].di2] : nullptr;
        ca.t[k].dst  = conv[k];
        ca.t[k].n    = n;
        ca.t[k].mode = ents[k].mode;
        size_t elems = (ents[k].mode == 3) ? (size_t)n * 2 : (size_t)n;  // f32 dst
        off += (elems + 63) & ~(size_t)63;
    }
    int* flag  = (int*)(ws + ((size_t)15 << 20));
    bf16* aggr = (bf16*)(ws + ((size_t)16 << 20));   // [N,128] (layer-1 only)
    bf16* Y    = (bf16*)(ws + ((size_t)30 << 20));   // [N,512] permuted
    bf16* h1   = (bf16*)(ws + ((size_t)84 << 20));   // [N,128]

    const bf16 *xc   = conv[0];
    const bf16 *Wp1  = conv[1],  *bp1 = conv[2];
    const bf16 *Wihp1 = conv[3], *Whh1 = conv[4];
    const float *bsum1 = (const float*)conv[5];
    const bf16 *Wl1 = conv[6], *bl1 = conv[7], *Wr1 = conv[8];
    const bf16 *Wp2 = conv[9], *bp2 = conv[10];
    const bf16 *Wihp2 = conv[11], *Whh2 = conv[12];
    const float *bsum2 = (const float*)conv[13];
    const bf16 *Wl2 = conv[14], *bl2 = conv[15], *Wr2 = conv[16];

    dim3 blk(256);
    const int gx = (N + 63) / 64;    // 782
    const int gl = N / 16;           // 3125 (exact)

    convert_inputs<<<dim3(1024), blk, 0, stream>>>(ca, flag);

    // ---- layer 1 ----
    fused_xp_y<<<dim3(gx), blk, 0, stream>>>(xc, Wp1, bp1, Wihp1, bsum1, Y, N);
    lstm_aggr<0><<<dim3(gl), dim3(512), 0, stream>>>(
        Y, es, Whh1, aggr, N, nullptr, nullptr, nullptr, nullptr, nullptr, nullptr);

    // ---- between layers: lin1 -> xp2 -> Y2 ----
    fused_lin_xp_y<<<dim3(gx), blk, 0, stream>>>(
        aggr, Wl1, bl1, xc, Wr1, h1, Wp2, bp2, Wihp2, bsum2, Y, N);

    // ---- layer 2 + fused final linear ----
    lstm_aggr<1><<<dim3(gl), dim3(512), 0, stream>>>(
        Y, es, Whh2, aggr, N, Wl2, bl2, Wr2, h1, d_out, flag);
}